// Round 7
// baseline (393.497 us; speedup 1.0000x reference)
//
#include <hip/hip_runtime.h>
#include <cstdint>
#include <cstddef>

// Problem constants
#define T_TOKENS 8192
#define DIM      1024
#define HID      2048
#define NE       8
#define HCAP     17408   // 16384 used rows + 8*128 max padding

typedef __attribute__((ext_vector_type(8))) short short8;
typedef __attribute__((ext_vector_type(4))) short short4v;
typedef __attribute__((ext_vector_type(4))) float f32x4;

__device__ __forceinline__ unsigned short f2bf(float f) {
  unsigned int u = __builtin_bit_cast(unsigned int, f);
  u += 0x7fffu + ((u >> 16) & 1u);   // RNE
  return (unsigned short)(u >> 16);
}

__device__ __forceinline__ void gload16(const void* g, void* lds) {
  __builtin_amdgcn_global_load_lds((const __attribute__((address_space(1))) void*)g,
                                   (__attribute__((address_space(3))) void*)lds,
                                   16, 0, 0);
}

// phase-end: counted vmcnt then raw barrier (memory-clobbered: fences reordering)
#define VMWB(N) do { asm volatile("s_waitcnt vmcnt(" #N ")" ::: "memory"); \
                     __builtin_amdgcn_s_barrier(); } while (0)
// phase-end without vmcnt (still memory-fenced)
#define PBARF() asm volatile("s_barrier" ::: "memory")
// phase-open: barrier then lgkm drain (m201 template form; NO sched_barrier —
// ds_reads here are normal loads, compiler tracks deps; m141: pinning regresses)
#define OPENP() do { __builtin_amdgcn_s_barrier(); \
                     asm volatile("s_waitcnt lgkmcnt(0)" ::: "memory"); } while (0)

// ------- weights [E][K][N] f32 -> [E][N][K] bf16 (transpose + convert) -------
__global__ void transcvt_kernel(const float* __restrict__ in, unsigned short* __restrict__ out,
                                int K, int N) {
  __shared__ float tile[64][65];
  int e = blockIdx.z;
  int r  = threadIdx.x >> 2;          // 0..63
  int c0 = (threadIdx.x & 3) * 16;    // 0,16,32,48
  const float* src = in + ((size_t)e * K + blockIdx.y * 64 + r) * N + blockIdx.x * 64 + c0;
#pragma unroll
  for (int j = 0; j < 4; j++) {
    float4 v = *(const float4*)(src + j * 4);
    tile[r][c0 + j * 4 + 0] = v.x; tile[r][c0 + j * 4 + 1] = v.y;
    tile[r][c0 + j * 4 + 2] = v.z; tile[r][c0 + j * 4 + 3] = v.w;
  }
  __syncthreads();
  short8 o0, o1;
#pragma unroll
  for (int j = 0; j < 8; j++) o0[j] = (short)f2bf(tile[c0 + j][r]);
#pragma unroll
  for (int j = 0; j < 8; j++) o1[j] = (short)f2bf(tile[c0 + 8 + j][r]);
  unsigned short* dst = out + ((size_t)e * N + blockIdx.x * 64 + r) * K + blockIdx.y * 64 + c0;
  *(short8*)dst = o0;
  *(short8*)(dst + 8) = o1;
}

// ------- gate phase A: logits (f64 accum) + top-2 softmax + x->bf16 fused -------
__global__ void gate_kernel(const float* __restrict__ x, const float* __restrict__ gw,
                            int2* __restrict__ sel, float2* __restrict__ wts,
                            unsigned short* __restrict__ xb) {
  int wid = threadIdx.x >> 6, lane = threadIdx.x & 63;
  int t = blockIdx.x * 4 + wid;
  const float* xr = x + (size_t)t * DIM;
  unsigned short* xo = xb + (size_t)t * DIM;
  double acc[NE];
#pragma unroll
  for (int e = 0; e < NE; e++) acc[e] = 0.0;
#pragma unroll
  for (int p = 0; p < 4; p++) {
    int idx = p * 256 + lane * 4;
    float4 xv = *(const float4*)(xr + idx);
    short4v o;
    o[0] = (short)f2bf(xv.x); o[1] = (short)f2bf(xv.y);
    o[2] = (short)f2bf(xv.z); o[3] = (short)f2bf(xv.w);
    *(short4v*)(xo + idx) = o;
#pragma unroll
    for (int e = 0; e < NE; e++) {
      float4 g = *(const float4*)(gw + e * DIM + idx);
      acc[e] += (double)xv.x * (double)g.x + (double)xv.y * (double)g.y
              + (double)xv.z * (double)g.z + (double)xv.w * (double)g.w;
    }
  }
#pragma unroll
  for (int e = 0; e < NE; e++) {
    double v = acc[e];
#pragma unroll
    for (int off = 32; off > 0; off >>= 1) v += __shfl_xor(v, off);
    acc[e] = v;
  }
  if (lane == 0) {
    float l[NE];
#pragma unroll
    for (int e = 0; e < NE; e++) l[e] = (float)acc[e];
    int i0 = 0; float v0 = l[0];
#pragma unroll
    for (int e = 1; e < NE; e++) if (l[e] > v0) { v0 = l[e]; i0 = e; }
    int i1 = -1; float v1 = -3.4e38f;
#pragma unroll
    for (int e = 0; e < NE; e++) if (e != i0 && l[e] > v1) { v1 = l[e]; i1 = e; }
    float ew = __expf(v1 - v0);          // v1 <= v0, stable
    float w0 = 1.0f / (1.0f + ew);
    float w1 = ew / (1.0f + ew);
    sel[t] = make_int2(i0, i1);
    wts[t] = make_float2(w0, w1);
  }
}

// ---------------- gate phase B: block-aggregated bucket scatter ----------------
__global__ void scatter_kernel(const int2* __restrict__ sel, const float2* __restrict__ wts,
                               int* __restrict__ cnt, int* __restrict__ btok,
                               float* __restrict__ bw) {
  __shared__ int hist[NE];
  __shared__ int base[NE];
  int tid = threadIdx.x;
  if (tid < NE) hist[tid] = 0;
  __syncthreads();
  int t = blockIdx.x * 256 + tid;
  int2 s = sel[t]; float2 w = wts[t];
  int p0 = atomicAdd(&hist[s.x], 1);
  int p1 = atomicAdd(&hist[s.y], 1);
  __syncthreads();
  if (tid < NE) base[tid] = atomicAdd(&cnt[tid], hist[tid]);
  __syncthreads();
  int o0 = base[s.x] + p0;
  btok[s.x * T_TOKENS + o0] = t; bw[s.x * T_TOKENS + o0] = w.x;
  int o1 = base[s.y] + p1;
  btok[s.y * T_TOKENS + o1] = t; bw[s.y * T_TOKENS + o1] = w.y;
}

// ---------------- GEMM1: h = silu(Xe@W1) * (Xe@W3), 8-phase dual-B ----------------
// BM=256, BN=128 dual (B1=w1, B3=w3 panels), BK=64; 512 thr = 8 waves (2M x 4N),
// wave tile 128M x 32N-dual. LDS 2 x 64KB dbuf:
//   [A half0 16K | A half1 16K | B1 16K | B3 16K]
// Phases: p0 = mlo x B1, p1 = mlo x B3, p2 = mhi x B1, p3 = mhi x B3 (16 MFMA ea).
// Stage order per K-step = CONSUMPTION order: [A0' B1' B3' A1'] at p0..p3.
// Waits (loads L1..L8 per step, in-order per wave):
//   steady: p0-end vmcnt(4) covers B3' of prev step; p1-end vmcnt(4) covers A1';
//           p2-end plain fenced barrier; p3-end vmcnt(4) covers next A0'+B1'.
//   drain:  (2, 0, plain, 0).
__global__ __launch_bounds__(512, 2) void gemm1_kernel(
    const unsigned short* __restrict__ xb, const unsigned short* __restrict__ w1t,
    const unsigned short* __restrict__ w3t, const int* __restrict__ cnt,
    const int* __restrict__ btok, const unsigned short* __restrict__ zbuf,
    unsigned short* __restrict__ h) {
  int e = blockIdx.z;
  int cn = cnt[e];
  int pc = (cn + 127) & ~127;
  int mt = blockIdx.y;
  if (mt * 256 >= pc) return;
  int hoff = 0;
#pragma unroll
  for (int i = 0; i < NE; i++) { int pi = (cnt[i] + 127) & ~127; if (i < e) hoff += pi; }
  int nt = blockIdx.x;

  __shared__ short8 ldsbuf[8192];   // 128 KB
  char* lds = (char*)ldsbuf;

  int tid = threadIdx.x, wid = tid >> 6, lane = tid & 63;
  int m0 = mt * 256;
  int wr = wid >> 2, wc = wid & 3;
  int l15 = lane & 15;

  // staging sources (pre-swizzled global k-column; T2 + rule #21)
  int s = wid * 8 + (lane >> 3);                    // 0..63
  int swzcol = ((lane & 7) ^ ((lane >> 3) & 7)) * 8;
  const unsigned short* asrc[4];
#pragma unroll
  for (int rd = 0; rd < 4; rd++) {
    int r = m0 + rd * 64 + s;
    asrc[rd] = (r < cn) ? (xb + (size_t)btok[e * T_TOKENS + r] * DIM + swzcol)
                        : (zbuf + swzcol);
  }
  const unsigned short* b1src[2]; const unsigned short* b3src[2];
#pragma unroll
  for (int rd = 0; rd < 2; rd++) {
    size_t o = ((size_t)e * HID + nt * 128 + rd * 64 + s) * DIM + swzcol;
    b1src[rd] = w1t + o; b3src[rd] = w3t + o;
  }
  int ldst = wid * 1024;   // WAVE-UNIFORM dest; HW appends lane*16

  // read-side offsets (XOR swizzle key = (slot&7)<<4 = (lane&7)<<4)
  int cb0 = ((lane >> 4) * 16) ^ ((lane & 7) << 4);
  int cb1 = (64 + (lane >> 4) * 16) ^ ((lane & 7) << 4);
  int offA  = wr * 8192 + l15 * 128;
  int offB1 = 32768 + wc * 4096 + l15 * 128;
  int offB3 = 49152 + wc * 4096 + l15 * 128;

  f32x4 zero = {0.f, 0.f, 0.f, 0.f};
  f32x4 acc1[8][2], acc3[8][2];
#pragma unroll
  for (int m = 0; m < 8; m++)
#pragma unroll
    for (int n = 0; n < 2; n++) { acc1[m][n] = zero; acc3[m][n] = zero; }
  short8 af[4][2], f1[2][2], f3[2][2];

#define S_A0 gload16(asrc[0] + ko, nb + ldst);           gload16(asrc[2] + ko, nb + 8192 + ldst)
#define S_A1 gload16(asrc[1] + ko, nb + 16384 + ldst);   gload16(asrc[3] + ko, nb + 24576 + ldst)
#define S_B1 gload16(b1src[0] + ko, nb + 32768 + ldst);  gload16(b1src[1] + ko, nb + 40960 + ldst)
#define S_B3 gload16(b3src[0] + ko, nb + 49152 + ldst);  gload16(b3src[1] + ko, nb + 57344 + ldst)

#define STEP1(CUR, NB, KO, STG, W0, W1, W3)                                      \
  {                                                                              \
    const char* cu = (CUR); char* nb = (NB); int ko = (KO);                      \
    (void)nb; (void)ko;                                                          \
    /* p0: read A-half0 + B1; stage A0' */                                       \
    _Pragma("unroll") for (int mm = 0; mm < 4; mm++) {                           \
      af[mm][0] = *(const short8*)(cu + offA + mm * 2048 + cb0);                 \
      af[mm][1] = *(const short8*)(cu + offA + mm * 2048 + cb1);                 \
    }                                                                            \
    _Pragma("unroll") for (int nn = 0; nn < 2; nn++) {                           \
      f1[nn][0] = *(const short8*)(cu + offB1 + nn * 2048 + cb0);                \
      f1[nn][1] = *(const short8*)(cu + offB1 + nn * 2048 + cb1);                \
    }                                                                            \
    if (STG) { S_A0; }                                                           \
    OPENP();                                                                     \
    __builtin_amdgcn_s_setprio(1);                                               \
    _Pragma("unroll") for (int mm = 0; mm < 4; mm++)                             \
      _Pragma("unroll") for (int nn = 0; nn < 2; nn++) {                         \
        acc1[mm][nn] = __builtin_amdgcn_mfma_f32_16x16x32_bf16(af[mm][0], f1[nn][0], acc1[mm][nn], 0, 0, 0); \
        acc1[mm][nn] = __builtin_amdgcn_mfma_f32_16x16x32_bf16(af[mm][1], f1[nn][1], acc1[mm][nn], 0, 0, 0); \
      }                                                                          \
    __builtin_amdgcn_s_setprio(0);                                               \
    VMWB(W0);                                                                    \
    /* p1: read B3; stage B1' */                                                 \
    _Pragma("unroll") for (int nn = 0; nn < 2; nn++) {                           \
      f3[nn][0] = *(const short8*)(cu + offB3 + nn * 2048 + cb0);                \
      f3[nn][1] = *(const short8*)(cu + offB3 + nn * 2048 + cb1);                \
    }                                                                            \
    if (STG) { S_B1; }                                                           \
    OPENP();                                                                     \
    __builtin_amdgcn_s_setprio(1);                                               \
    _Pragma("unroll") for (int mm = 0; mm < 4; mm++)                             \
      _Pragma("unroll") for (int nn = 0; nn < 2; nn++) {                         \
        acc3[mm][nn] = __builtin_amdgcn_mfma_f32_16x16x32_bf16(af[mm][0], f3[nn][0], acc3[mm][nn], 0, 0, 0); \
        acc3[mm][nn] = __builtin_amdgcn_mfma_f32_16x16x32_bf16(af[mm][1], f3[nn][1], acc3[mm][nn], 0, 0, 0); \
      }                                                                          \
    __builtin_amdgcn_s_setprio(0);                                               \
    VMWB(W1);                                                                    \
    /* p2: read A-half1 (overwrite af); stage B3' */                             \
    _Pragma("unroll") for (int mm = 0; mm < 4; mm++) {                           \
      af[mm][0] = *(const short8*)(cu + 16384 + offA + mm * 2048 + cb0);         \
      af[mm][1] = *(const short8*)(cu + 16384 + offA + mm * 2048 + cb1);         \
    }                                                                            \
    if (STG) { S_B3; }                                                           \
    OPENP();                                                                     \
    __builtin_amdgcn_s_setprio(1);                                               \
    _Pragma("unroll") for (int mm = 0; mm < 4; mm++)                             \
      _Pragma("unroll") for (int nn = 0; nn < 2; nn++) {                         \
        acc1[4 + mm][nn] = __builtin_amdgcn_mfma_f32_16x16x32_bf16(af[mm][0], f1[nn][0], acc1[4 + mm][nn], 0, 0, 0); \
        acc1[4 + mm][nn] = __builtin_amdgcn_mfma_f32_16x16x32_bf16(af[mm][1], f1[nn][1], acc1[4 + mm][nn], 0, 0, 0); \
      }                                                                          \
    __builtin_amdgcn_s_setprio(0);                                               \
    PBARF();                                                                     \
    /* p3: stage A1' */                                                          \
    if (STG) { S_A1; }                                                           \
    OPENP();                                                                     \
    __builtin_amdgcn_s_setprio(1);                                               \
    _Pragma("unroll") for (int mm = 0; mm < 4; mm++)                             \
      _Pragma("unroll") for (int nn = 0; nn < 2; nn++) {                         \
        acc3[4 + mm][nn] = __builtin_amdgcn_mfma_f32_16x16x32_bf16(af[mm][0], f3[nn][0], acc3[4 + mm][nn], 0, 0, 0); \
        acc3[4 + mm][nn] = __builtin_amdgcn_mfma_f32_16x16x32_bf16(af[mm][1], f3[nn][1], acc3[4 + mm][nn], 0, 0, 0); \
      }                                                                          \
    __builtin_amdgcn_s_setprio(0);                                               \
    VMWB(W3);                                                                    \
  }

  // prologue: stage K-step 0 into buf0 in consumption order [A0 B1 B3 A1]
  {
    char* nb = lds; int ko = 0;
    S_A0; S_B1; S_B3; S_A1;
  }
  VMWB(4);   // A0 + B1 of step 0 landed; B3, A1 still in flight

#pragma unroll 1
  for (int kt = 0; kt < 14; kt += 2) {
    int ko0 = (kt + 1) * 64;
    STEP1(lds, lds + 65536, ko0, true, 4, 4, 4);
    STEP1(lds + 65536, lds, ko0 + 64, true, 4, 4, 4);
  }
  STEP1(lds, lds + 65536, 15 * 64, true, 4, 4, 4);
  STEP1(lds + 65536, lds, 0, false, 2, 0, 0);

  // ---- epilogue: lane-local silu combine, guarded store ----
#pragma unroll
  for (int m = 0; m < 8; m++)
#pragma unroll
    for (int n = 0; n < 2; n++)
#pragma unroll
      for (int j = 0; j < 4; j++) {
        float s1 = acc1[m][n][j], s3 = acc3[m][n][j];
        float hv = s1 / (1.0f + __expf(-s1)) * s3;   // silu(s1)*s3
        int row = wr * 128 + m * 16 + (lane >> 4) * 4 + j;
        if (m0 + row < pc) {
          int col = nt * 128 + wc * 32 + n * 16 + l15;
          h[(size_t)(hoff + m0 + row) * HID + col] = f2bf(hv);
        }
      }
#undef S_A0
#undef S_A1
#undef S_B1
#undef S_B3
}

// ---------------- GEMM2: y = h @ W2, scale by gate weight, atomic combine ----------------
// (proven round-2 version) block tile 128(M) x 128(N), BK=64, 4 waves 2x2
__global__ __launch_bounds__(256, 2) void gemm2_kernel(
    const unsigned short* __restrict__ h, const unsigned short* __restrict__ w2t,
    const int* __restrict__ cnt, const int* __restrict__ btok,
    const float* __restrict__ bw, float* __restrict__ out) {
  int e = blockIdx.z;
  int cn = cnt[e];
  int pc = (cn + 127) & ~127;
  int mt = blockIdx.y;
  if (mt * 128 >= pc) return;
  int hoff = 0;
#pragma unroll
  for (int i = 0; i < NE; i++) { int pi = (cnt[i] + 127) & ~127; if (i < e) hoff += pi; }
  int nt = blockIdx.x;

  __shared__ short8 At8[1024];  // [128][64]
  __shared__ short8 Bt8[1024];  // [128][64]

  int tid = threadIdx.x, wid = tid >> 6, lane = tid & 63;
  int m0 = mt * 128;

  int swzcol = ((lane & 7) ^ (lane >> 3)) * 8;

  const unsigned short* as[4]; const unsigned short* bs[4];
#pragma unroll
  for (int rd = 0; rd < 4; rd++) {
    int row = (rd * 4 + wid) * 8 + (lane >> 3);
    as[rd] = h + (size_t)(hoff + m0 + row) * HID + swzcol;
    bs[rd] = w2t + ((size_t)e * DIM + nt * 128 + row) * HID + swzcol;
  }

  f32x4 zero = {0.f, 0.f, 0.f, 0.f};
  f32x4 acc[4][4];
#pragma unroll
  for (int m = 0; m < 4; m++)
#pragma unroll
    for (int n = 0; n < 4; n++) acc[m][n] = zero;

  int wr = wid >> 1, wc = wid & 1;
  const char* At = (const char*)At8;
  const char* Bt = (const char*)Bt8;
  int lxor = (lane & 7) << 4;

  for (int kt = 0; kt < HID / 64; kt++) {
    int ko = kt * 64;
#pragma unroll
    for (int rd = 0; rd < 4; rd++) {
      gload16(as[rd] + ko, (char*)At8 + (rd * 4 + wid) * 1024);
      gload16(bs[rd] + ko, (char*)Bt8 + (rd * 4 + wid) * 1024);
    }
    __syncthreads();
#pragma unroll
    for (int ks = 0; ks < 2; ks++) {
      int cb = (ks * 64 + (lane >> 4) * 16) ^ lxor;
      short8 a[4], b[4];
#pragma unroll
      for (int m = 0; m < 4; m++)
        a[m] = *(const short8*)(At + (wr * 64 + m * 16 + (lane & 15)) * 128 + cb);
#pragma unroll
      for (int n = 0; n < 4; n++)
        b[n] = *(const short8*)(Bt + (wc * 64 + n * 16 + (lane & 15)) * 128 + cb);
#pragma unroll
      for (int m = 0; m < 4; m++)
#pragma unroll
        for (int n = 0; n < 4; n++)
          acc[m][n] = __builtin_amdgcn_mfma_f32_16x16x32_bf16(a[m], b[n], acc[m][n], 0, 0, 0);
    }
    __syncthreads();
  }

#pragma unroll
  for (int m = 0; m < 4; m++)
#pragma unroll
    for (int j = 0; j < 4; j++) {
      int r = m0 + wr * 64 + m * 16 + (lane >> 4) * 4 + j;
      if (r < cn) {
        int t = btok[e * T_TOKENS + r];
        float w = bw[e * T_TOKENS + r];
        size_t ob = (size_t)t * DIM + nt * 128 + wc * 64 + (lane & 15);
#pragma unroll
        for (int n = 0; n < 4; n++)
          atomicAdd(out + ob + n * 16, w * acc[m][n][j]);
      }
    }
}

extern "C" void kernel_launch(void* const* d_in, const int* in_sizes, int n_in,
                              void* d_out, int out_size, void* d_ws, size_t ws_size,
                              hipStream_t stream) {
  const float* x  = (const float*)d_in[0];
  const float* gw = (const float*)d_in[1];
  const float* w1 = (const float*)d_in[2];
  const float* w3 = (const float*)d_in[3];
  const float* w2 = (const float*)d_in[4];
  float* out = (float*)d_out;

  // workspace layout (~190 MiB total)
  char* ws = (char*)d_ws;
  unsigned short* W1T = (unsigned short*)ws;                      // [8][2048][1024] bf16
  unsigned short* W3T = W1T + (size_t)NE * HID * DIM;             // [8][2048][1024]
  unsigned short* W2T = W3T + (size_t)NE * HID * DIM;             // [8][1024][2048]
  unsigned short* XB  = W2T + (size_t)NE * DIM * HID;             // [8192][1024]
  unsigned short* H   = XB + (size_t)T_TOKENS * DIM;              // [17408][2048]
  int*   TOK = (int*)(H + (size_t)HCAP * HID);                    // [8][8192]
  float* BW  = (float*)(TOK + NE * T_TOKENS);                     // [8][8192]
  int*   CNT = (int*)(BW + NE * T_TOKENS);                        // [16]
  unsigned short* ZBUF = (unsigned short*)(CNT + 16);             // [1024] zeros
  int2*   SEL = (int2*)(ZBUF + 1024);                             // [8192]
  float2* WTS = (float2*)(SEL + T_TOKENS);                        // [8192]

  hipMemsetAsync(d_out, 0, (size_t)out_size * sizeof(float), stream);
  hipMemsetAsync(CNT, 0, 16 * sizeof(int) + 1024 * sizeof(unsigned short), stream);

  gate_kernel<<<T_TOKENS / 4, 256, 0, stream>>>(x, gw, SEL, WTS, XB);
  scatter_kernel<<<T_TOKENS / 256, 256, 0, stream>>>(SEL, WTS, CNT, TOK, BW);
  transcvt_kernel<<<dim3(HID / 64, DIM / 64, NE), 256, 0, stream>>>(w1, W1T, DIM, HID);
  transcvt_kernel<<<dim3(HID / 64, DIM / 64, NE), 256, 0, stream>>>(w3, W3T, DIM, HID);
  transcvt_kernel<<<dim3(DIM / 64, HID / 64, NE), 256, 0, stream>>>(w2, W2T, HID, DIM);
  gemm1_kernel<<<dim3(HID / 128, 32, NE), 512, 0, stream>>>(XB, W1T, W3T, CNT, TOK, ZBUF, H);
  gemm2_kernel<<<dim3(DIM / 128, 64, NE), 256, 0, stream>>>(H, W2T, CNT, TOK, BW, out);
}

// Round 8
// 377.286 us; speedup vs baseline: 1.0430x; 1.0430x over previous
//
#include <hip/hip_runtime.h>
#include <cstdint>
#include <cstddef>

// Problem constants
#define T_TOKENS 8192
#define DIM      1024
#define HID      2048
#define NE       8
#define HCAP     17408   // 16384 used rows + 8*128 max padding

typedef __attribute__((ext_vector_type(8))) short short8;
typedef __attribute__((ext_vector_type(4))) short short4v;
typedef __attribute__((ext_vector_type(4))) float f32x4;

__device__ __forceinline__ unsigned short f2bf(float f) {
  unsigned int u = __builtin_bit_cast(unsigned int, f);
  u += 0x7fffu + ((u >> 16) & 1u);   // RNE
  return (unsigned short)(u >> 16);
}

__device__ __forceinline__ void gload16(const void* g, void* lds) {
  __builtin_amdgcn_global_load_lds((const __attribute__((address_space(1))) void*)g,
                                   (__attribute__((address_space(3))) void*)lds,
                                   16, 0, 0);
}

// ------- weights [E][K][N] f32 -> [E][N][K] bf16 (transpose + convert) -------
__global__ void transcvt_kernel(const float* __restrict__ in, unsigned short* __restrict__ out,
                                int K, int N) {
  __shared__ float tile[64][65];
  int e = blockIdx.z;
  int r  = threadIdx.x >> 2;          // 0..63
  int c0 = (threadIdx.x & 3) * 16;    // 0,16,32,48
  const float* src = in + ((size_t)e * K + blockIdx.y * 64 + r) * N + blockIdx.x * 64 + c0;
#pragma unroll
  for (int j = 0; j < 4; j++) {
    float4 v = *(const float4*)(src + j * 4);
    tile[r][c0 + j * 4 + 0] = v.x; tile[r][c0 + j * 4 + 1] = v.y;
    tile[r][c0 + j * 4 + 2] = v.z; tile[r][c0 + j * 4 + 3] = v.w;
  }
  __syncthreads();
  short8 o0, o1;
#pragma unroll
  for (int j = 0; j < 8; j++) o0[j] = (short)f2bf(tile[c0 + j][r]);
#pragma unroll
  for (int j = 0; j < 8; j++) o1[j] = (short)f2bf(tile[c0 + 8 + j][r]);
  unsigned short* dst = out + ((size_t)e * N + blockIdx.x * 64 + r) * K + blockIdx.y * 64 + c0;
  *(short8*)dst = o0;
  *(short8*)(dst + 8) = o1;
}

// ------- gate phase A: logits (f64 accum) + top-2 softmax + x->bf16 fused -------
__global__ void gate_kernel(const float* __restrict__ x, const float* __restrict__ gw,
                            int2* __restrict__ sel, float2* __restrict__ wts,
                            unsigned short* __restrict__ xb) {
  int wid = threadIdx.x >> 6, lane = threadIdx.x & 63;
  int t = blockIdx.x * 4 + wid;
  const float* xr = x + (size_t)t * DIM;
  unsigned short* xo = xb + (size_t)t * DIM;
  double acc[NE];
#pragma unroll
  for (int e = 0; e < NE; e++) acc[e] = 0.0;
#pragma unroll
  for (int p = 0; p < 4; p++) {
    int idx = p * 256 + lane * 4;
    float4 xv = *(const float4*)(xr + idx);
    short4v o;
    o[0] = (short)f2bf(xv.x); o[1] = (short)f2bf(xv.y);
    o[2] = (short)f2bf(xv.z); o[3] = (short)f2bf(xv.w);
    *(short4v*)(xo + idx) = o;
#pragma unroll
    for (int e = 0; e < NE; e++) {
      float4 g = *(const float4*)(gw + e * DIM + idx);
      acc[e] += (double)xv.x * (double)g.x + (double)xv.y * (double)g.y
              + (double)xv.z * (double)g.z + (double)xv.w * (double)g.w;
    }
  }
#pragma unroll
  for (int e = 0; e < NE; e++) {
    double v = acc[e];
#pragma unroll
    for (int off = 32; off > 0; off >>= 1) v += __shfl_xor(v, off);
    acc[e] = v;
  }
  if (lane == 0) {
    float l[NE];
#pragma unroll
    for (int e = 0; e < NE; e++) l[e] = (float)acc[e];
    int i0 = 0; float v0 = l[0];
#pragma unroll
    for (int e = 1; e < NE; e++) if (l[e] > v0) { v0 = l[e]; i0 = e; }
    int i1 = -1; float v1 = -3.4e38f;
#pragma unroll
    for (int e = 0; e < NE; e++) if (e != i0 && l[e] > v1) { v1 = l[e]; i1 = e; }
    float ew = __expf(v1 - v0);          // v1 <= v0, stable
    float w0 = 1.0f / (1.0f + ew);
    float w1 = ew / (1.0f + ew);
    sel[t] = make_int2(i0, i1);
    wts[t] = make_float2(w0, w1);
  }
}

// ---------------- gate phase B: block-aggregated bucket scatter ----------------
__global__ void scatter_kernel(const int2* __restrict__ sel, const float2* __restrict__ wts,
                               int* __restrict__ cnt, int* __restrict__ btok,
                               float* __restrict__ bw) {
  __shared__ int hist[NE];
  __shared__ int base[NE];
  int tid = threadIdx.x;
  if (tid < NE) hist[tid] = 0;
  __syncthreads();
  int t = blockIdx.x * 256 + tid;
  int2 s = sel[t]; float2 w = wts[t];
  int p0 = atomicAdd(&hist[s.x], 1);
  int p1 = atomicAdd(&hist[s.y], 1);
  __syncthreads();
  if (tid < NE) base[tid] = atomicAdd(&cnt[tid], hist[tid]);
  __syncthreads();
  int o0 = base[s.x] + p0;
  btok[s.x * T_TOKENS + o0] = t; bw[s.x * T_TOKENS + o0] = w.x;
  int o1 = base[s.y] + p1;
  btok[s.y * T_TOKENS + o1] = t; bw[s.y * T_TOKENS + o1] = w.y;
}

// ---------------- GEMM1: h = silu(Xe@W1) * (Xe@W3), gathered rows, fused ----------------
// Proven round-2 inner structure: block tile 128(M) x 64(N), BK=64, 4 waves 2x2,
// dual B (w1,w3), T2 swizzle. NEW: 1D grid + bijective XCD-chunk swizzle (m204),
// decode with mt FASTEST so all mt-sharers of a B panel land on one XCD's L2.
#define G1_NT (HID / 64)     // 32
#define G1_MT 64
#define G1_NWG (G1_NT * G1_MT * NE)   // 16384, %8==0
__global__ __launch_bounds__(256, 2) void gemm1_kernel(
    const unsigned short* __restrict__ xb, const unsigned short* __restrict__ w1t,
    const unsigned short* __restrict__ w3t, const int* __restrict__ cnt,
    const int* __restrict__ btok, const unsigned short* __restrict__ zbuf,
    unsigned short* __restrict__ h) {
  // XCD-chunk remap: bid -> wg (bijective since G1_NWG % 8 == 0)
  int bid = blockIdx.x;
  int wg = (bid & 7) * (G1_NWG / 8) + (bid >> 3);
  int e  = wg / (G1_NT * G1_MT);
  int rem = wg % (G1_NT * G1_MT);
  int nt = rem / G1_MT;        // B panel index (slow)
  int mt = rem % G1_MT;        // M tile (fast -> B-sharers contiguous per XCD)

  int cn = cnt[e];
  int pc = (cn + 127) & ~127;
  if (mt * 128 >= pc) return;
  int hoff = 0;
#pragma unroll
  for (int i = 0; i < NE; i++) { int pi = (cnt[i] + 127) & ~127; if (i < e) hoff += pi; }

  __shared__ short8 At8[1024];  // [128][64] bf16
  __shared__ short8 B18[512];   // [64][64]
  __shared__ short8 B38[512];   // [64][64]

  int tid = threadIdx.x, wid = tid >> 6, lane = tid & 63;
  int m0 = mt * 128;

  // pre-swizzled global source column (T2 + rule #21)
  int swzcol = ((lane & 7) ^ (lane >> 3)) * 8;

  const unsigned short* asrc[4];
#pragma unroll
  for (int rd = 0; rd < 4; rd++) {
    int row = (rd * 4 + wid) * 8 + (lane >> 3);
    int r = m0 + row;
    asrc[rd] = (r < cn) ? (xb + (size_t)btok[e * T_TOKENS + r] * DIM + swzcol)
                        : (zbuf + swzcol);
  }
  const unsigned short* b1s[2]; const unsigned short* b3s[2];
#pragma unroll
  for (int rd = 0; rd < 2; rd++) {
    int row = (rd * 4 + wid) * 8 + (lane >> 3);
    size_t o = ((size_t)e * HID + nt * 64 + row) * DIM + swzcol;
    b1s[rd] = w1t + o; b3s[rd] = w3t + o;
  }

  f32x4 zero = {0.f, 0.f, 0.f, 0.f};
  f32x4 acc1[4][2], acc3[4][2];
#pragma unroll
  for (int m = 0; m < 4; m++)
#pragma unroll
    for (int n = 0; n < 2; n++) { acc1[m][n] = zero; acc3[m][n] = zero; }

  int wr = wid >> 1, wc = wid & 1;
  const char* At = (const char*)At8;
  const char* B1 = (const char*)B18;
  const char* B3 = (const char*)B38;
  int lxor = (lane & 7) << 4;   // read-side XOR key

  for (int kt = 0; kt < DIM / 64; kt++) {
    int ko = kt * 64;
#pragma unroll
    for (int rd = 0; rd < 4; rd++)
      gload16(asrc[rd] + ko, (char*)At8 + (rd * 4 + wid) * 1024);
#pragma unroll
    for (int rd = 0; rd < 2; rd++) {
      gload16(b1s[rd] + ko, (char*)B18 + (rd * 4 + wid) * 1024);
      gload16(b3s[rd] + ko, (char*)B38 + (rd * 4 + wid) * 1024);
    }
    __syncthreads();
#pragma unroll
    for (int ks = 0; ks < 2; ks++) {
      int cb = (ks * 64 + (lane >> 4) * 16) ^ lxor;
      short8 a[4], f1[2], f3[2];
#pragma unroll
      for (int m = 0; m < 4; m++)
        a[m] = *(const short8*)(At + (wr * 64 + m * 16 + (lane & 15)) * 128 + cb);
#pragma unroll
      for (int n = 0; n < 2; n++) {
        int rb = (wc * 32 + n * 16 + (lane & 15)) * 128 + cb;
        f1[n] = *(const short8*)(B1 + rb);
        f3[n] = *(const short8*)(B3 + rb);
      }
#pragma unroll
      for (int m = 0; m < 4; m++)
#pragma unroll
        for (int n = 0; n < 2; n++) {
          acc1[m][n] = __builtin_amdgcn_mfma_f32_16x16x32_bf16(a[m], f1[n], acc1[m][n], 0, 0, 0);
          acc3[m][n] = __builtin_amdgcn_mfma_f32_16x16x32_bf16(a[m], f3[n], acc3[m][n], 0, 0, 0);
        }
    }
    __syncthreads();
  }

#pragma unroll
  for (int m = 0; m < 4; m++)
#pragma unroll
    for (int n = 0; n < 2; n++) {
#pragma unroll
      for (int j = 0; j < 4; j++) {
        float s1 = acc1[m][n][j], s3 = acc3[m][n][j];
        float hv = s1 / (1.0f + __expf(-s1)) * s3;   // silu(s1)*s3
        int row = wr * 64 + m * 16 + (lane >> 4) * 4 + j;
        int col = nt * 64 + wc * 32 + n * 16 + (lane & 15);
        h[(size_t)(hoff + m0 + row) * HID + col] = f2bf(hv);
      }
    }
}

// ---------------- GEMM2: y = h @ W2, scale by gate weight, atomic combine ----------------
// Proven round-2 inner structure: block tile 128(M) x 128(N), BK=64, 4 waves 2x2.
// NEW: same 1D-grid XCD-chunk swizzle, mt fastest.
#define G2_NT (DIM / 128)    // 8
#define G2_MT 64
#define G2_NWG (G2_NT * G2_MT * NE)   // 4096, %8==0
__global__ __launch_bounds__(256, 2) void gemm2_kernel(
    const unsigned short* __restrict__ h, const unsigned short* __restrict__ w2t,
    const int* __restrict__ cnt, const int* __restrict__ btok,
    const float* __restrict__ bw, float* __restrict__ out) {
  int bid = blockIdx.x;
  int wg = (bid & 7) * (G2_NWG / 8) + (bid >> 3);
  int e  = wg / (G2_NT * G2_MT);
  int rem = wg % (G2_NT * G2_MT);
  int nt = rem / G2_MT;
  int mt = rem % G2_MT;

  int cn = cnt[e];
  int pc = (cn + 127) & ~127;
  if (mt * 128 >= pc) return;
  int hoff = 0;
#pragma unroll
  for (int i = 0; i < NE; i++) { int pi = (cnt[i] + 127) & ~127; if (i < e) hoff += pi; }

  __shared__ short8 At8[1024];  // [128][64]
  __shared__ short8 Bt8[1024];  // [128][64]

  int tid = threadIdx.x, wid = tid >> 6, lane = tid & 63;
  int m0 = mt * 128;

  int swzcol = ((lane & 7) ^ (lane >> 3)) * 8;

  const unsigned short* as[4]; const unsigned short* bs[4];
#pragma unroll
  for (int rd = 0; rd < 4; rd++) {
    int row = (rd * 4 + wid) * 8 + (lane >> 3);
    as[rd] = h + (size_t)(hoff + m0 + row) * HID + swzcol;
    bs[rd] = w2t + ((size_t)e * DIM + nt * 128 + row) * HID + swzcol;
  }

  f32x4 zero = {0.f, 0.f, 0.f, 0.f};
  f32x4 acc[4][4];
#pragma unroll
  for (int m = 0; m < 4; m++)
#pragma unroll
    for (int n = 0; n < 4; n++) acc[m][n] = zero;

  int wr = wid >> 1, wc = wid & 1;
  const char* At = (const char*)At8;
  const char* Bt = (const char*)Bt8;
  int lxor = (lane & 7) << 4;

  for (int kt = 0; kt < HID / 64; kt++) {
    int ko = kt * 64;
#pragma unroll
    for (int rd = 0; rd < 4; rd++) {
      gload16(as[rd] + ko, (char*)At8 + (rd * 4 + wid) * 1024);
      gload16(bs[rd] + ko, (char*)Bt8 + (rd * 4 + wid) * 1024);
    }
    __syncthreads();
#pragma unroll
    for (int ks = 0; ks < 2; ks++) {
      int cb = (ks * 64 + (lane >> 4) * 16) ^ lxor;
      short8 a[4], b[4];
#pragma unroll
      for (int m = 0; m < 4; m++)
        a[m] = *(const short8*)(At + (wr * 64 + m * 16 + (lane & 15)) * 128 + cb);
#pragma unroll
      for (int n = 0; n < 4; n++)
        b[n] = *(const short8*)(Bt + (wc * 64 + n * 16 + (lane & 15)) * 128 + cb);
#pragma unroll
      for (int m = 0; m < 4; m++)
#pragma unroll
        for (int n = 0; n < 4; n++)
          acc[m][n] = __builtin_amdgcn_mfma_f32_16x16x32_bf16(a[m], b[n], acc[m][n], 0, 0, 0);
    }
    __syncthreads();
  }

#pragma unroll
  for (int m = 0; m < 4; m++)
#pragma unroll
    for (int j = 0; j < 4; j++) {
      int r = m0 + wr * 64 + m * 16 + (lane >> 4) * 4 + j;
      if (r < cn) {
        int t = btok[e * T_TOKENS + r];
        float w = bw[e * T_TOKENS + r];
        size_t ob = (size_t)t * DIM + nt * 128 + wc * 64 + (lane & 15);
#pragma unroll
        for (int n = 0; n < 4; n++)
          atomicAdd(out + ob + n * 16, w * acc[m][n][j]);
      }
    }
}

extern "C" void kernel_launch(void* const* d_in, const int* in_sizes, int n_in,
                              void* d_out, int out_size, void* d_ws, size_t ws_size,
                              hipStream_t stream) {
  const float* x  = (const float*)d_in[0];
  const float* gw = (const float*)d_in[1];
  const float* w1 = (const float*)d_in[2];
  const float* w3 = (const float*)d_in[3];
  const float* w2 = (const float*)d_in[4];
  float* out = (float*)d_out;

  // workspace layout (~190 MiB total)
  char* ws = (char*)d_ws;
  unsigned short* W1T = (unsigned short*)ws;                      // [8][2048][1024] bf16
  unsigned short* W3T = W1T + (size_t)NE * HID * DIM;             // [8][2048][1024]
  unsigned short* W2T = W3T + (size_t)NE * HID * DIM;             // [8][1024][2048]
  unsigned short* XB  = W2T + (size_t)NE * DIM * HID;             // [8192][1024]
  unsigned short* H   = XB + (size_t)T_TOKENS * DIM;              // [17408][2048]
  int*   TOK = (int*)(H + (size_t)HCAP * HID);                    // [8][8192]
  float* BW  = (float*)(TOK + NE * T_TOKENS);                     // [8][8192]
  int*   CNT = (int*)(BW + NE * T_TOKENS);                        // [16]
  unsigned short* ZBUF = (unsigned short*)(CNT + 16);             // [1024] zeros
  int2*   SEL = (int2*)(ZBUF + 1024);                             // [8192]
  float2* WTS = (float2*)(SEL + T_TOKENS);                        // [8192]

  hipMemsetAsync(d_out, 0, (size_t)out_size * sizeof(float), stream);
  hipMemsetAsync(CNT, 0, 16 * sizeof(int) + 1024 * sizeof(unsigned short), stream);

  gate_kernel<<<T_TOKENS / 4, 256, 0, stream>>>(x, gw, SEL, WTS, XB);
  scatter_kernel<<<T_TOKENS / 256, 256, 0, stream>>>(SEL, WTS, CNT, TOK, BW);
  transcvt_kernel<<<dim3(HID / 64, DIM / 64, NE), 256, 0, stream>>>(w1, W1T, DIM, HID);
  transcvt_kernel<<<dim3(HID / 64, DIM / 64, NE), 256, 0, stream>>>(w3, W3T, DIM, HID);
  transcvt_kernel<<<dim3(DIM / 64, HID / 64, NE), 256, 0, stream>>>(w2, W2T, HID, DIM);
  gemm1_kernel<<<G1_NWG, 256, 0, stream>>>(XB, W1T, W3T, CNT, TOK, ZBUF, H);
  gemm2_kernel<<<G2_NWG, 256, 0, stream>>>(H, W2T, CNT, TOK, BW, out);
}

// Round 9
// 357.416 us; speedup vs baseline: 1.1009x; 1.0556x over previous
//
#include <hip/hip_runtime.h>
#include <cstdint>
#include <cstddef>

// Problem constants
#define T_TOKENS 8192
#define DIM      1024
#define HID      2048
#define NE       8
#define HCAP     17408   // 16384 used rows + 8*128 max padding

typedef __attribute__((ext_vector_type(8))) short short8;
typedef __attribute__((ext_vector_type(4))) short short4v;
typedef __attribute__((ext_vector_type(4))) float f32x4;

__device__ __forceinline__ unsigned short f2bf(float f) {
  unsigned int u = __builtin_bit_cast(unsigned int, f);
  u += 0x7fffu + ((u >> 16) & 1u);   // RNE
  return (unsigned short)(u >> 16);
}

__device__ __forceinline__ void gload16(const void* g, void* lds) {
  __builtin_amdgcn_global_load_lds((const __attribute__((address_space(1))) void*)g,
                                   (__attribute__((address_space(3))) void*)lds,
                                   16, 0, 0);
}

// ---------------- prep: fused {transcvt w1, w3, w2} + {gate} ----------------
// blocks [0,4096)        : w1 [E][K=1024][N=2048] -> W1T [E][N][K]
// blocks [4096,8192)     : w3 (same shape)
// blocks [8192,12288)    : w2 [E][K=2048][N=1024] -> W2T [E][N][K]
// blocks [12288,14336)   : gate (logits f64 + top-2 softmax + x->bf16)
#define PREP_GATE0 12288
__device__ __forceinline__ void transcvt_body(
    const float* __restrict__ in, unsigned short* __restrict__ out,
    int K, int N, int bx, int by, int e, float (*tile)[65], int tid) {
  int r  = tid >> 2;          // 0..63
  int c0 = (tid & 3) * 16;    // 0,16,32,48
  const float* src = in + ((size_t)e * K + by * 64 + r) * N + bx * 64 + c0;
#pragma unroll
  for (int j = 0; j < 4; j++) {
    float4 v = *(const float4*)(src + j * 4);
    tile[r][c0 + j * 4 + 0] = v.x; tile[r][c0 + j * 4 + 1] = v.y;
    tile[r][c0 + j * 4 + 2] = v.z; tile[r][c0 + j * 4 + 3] = v.w;
  }
  __syncthreads();
  short8 o0, o1;
#pragma unroll
  for (int j = 0; j < 8; j++) o0[j] = (short)f2bf(tile[c0 + j][r]);
#pragma unroll
  for (int j = 0; j < 8; j++) o1[j] = (short)f2bf(tile[c0 + 8 + j][r]);
  unsigned short* dst = out + ((size_t)e * N + bx * 64 + r) * K + by * 64 + c0;
  *(short8*)dst = o0;
  *(short8*)(dst + 8) = o1;
}

__global__ __launch_bounds__(256) void prep_kernel(
    const float* __restrict__ x, const float* __restrict__ gw,
    const float* __restrict__ w1, const float* __restrict__ w3,
    const float* __restrict__ w2,
    unsigned short* __restrict__ W1T, unsigned short* __restrict__ W3T,
    unsigned short* __restrict__ W2T,
    int2* __restrict__ sel, float2* __restrict__ wts,
    unsigned short* __restrict__ xb) {
  __shared__ float tile[64][65];
  int bid = blockIdx.x, tid = threadIdx.x;

  if (bid < PREP_GATE0) {
    // ---- weight transpose+convert ----
    if (bid < 4096) {
      int t = bid;
      transcvt_body(w1, W1T, DIM, HID, t % 32, (t / 32) % 16, t / 512, tile, tid);
    } else if (bid < 8192) {
      int t = bid - 4096;
      transcvt_body(w3, W3T, DIM, HID, t % 32, (t / 32) % 16, t / 512, tile, tid);
    } else {
      int t = bid - 8192;
      transcvt_body(w2, W2T, HID, DIM, t % 16, (t / 16) % 32, t / 512, tile, tid);
    }
    return;
  }

  // ---- gate: one wave per token ----
  int wid = tid >> 6, lane = tid & 63;
  int t = (bid - PREP_GATE0) * 4 + wid;
  const float* xr = x + (size_t)t * DIM;
  unsigned short* xo = xb + (size_t)t * DIM;
  double acc[NE];
#pragma unroll
  for (int e = 0; e < NE; e++) acc[e] = 0.0;
#pragma unroll
  for (int p = 0; p < 4; p++) {
    int idx = p * 256 + lane * 4;
    float4 xv = *(const float4*)(xr + idx);
    short4v o;
    o[0] = (short)f2bf(xv.x); o[1] = (short)f2bf(xv.y);
    o[2] = (short)f2bf(xv.z); o[3] = (short)f2bf(xv.w);
    *(short4v*)(xo + idx) = o;
#pragma unroll
    for (int e = 0; e < NE; e++) {
      float4 g = *(const float4*)(gw + e * DIM + idx);
      acc[e] += (double)xv.x * (double)g.x + (double)xv.y * (double)g.y
              + (double)xv.z * (double)g.z + (double)xv.w * (double)g.w;
    }
  }
#pragma unroll
  for (int e = 0; e < NE; e++) {
    double v = acc[e];
#pragma unroll
    for (int off = 32; off > 0; off >>= 1) v += __shfl_xor(v, off);
    acc[e] = v;
  }
  if (lane == 0) {
    float l[NE];
#pragma unroll
    for (int e = 0; e < NE; e++) l[e] = (float)acc[e];
    int i0 = 0; float v0 = l[0];
#pragma unroll
    for (int e = 1; e < NE; e++) if (l[e] > v0) { v0 = l[e]; i0 = e; }
    int i1 = -1; float v1 = -3.4e38f;
#pragma unroll
    for (int e = 0; e < NE; e++) if (e != i0 && l[e] > v1) { v1 = l[e]; i1 = e; }
    float ew = __expf(v1 - v0);          // v1 <= v0, stable
    float w0 = 1.0f / (1.0f + ew);
    float w1v = ew / (1.0f + ew);
    sel[t] = make_int2(i0, i1);
    wts[t] = make_float2(w0, w1v);
  }
}

// ---------------- gate phase B: block-aggregated bucket scatter ----------------
__global__ void scatter_kernel(const int2* __restrict__ sel, const float2* __restrict__ wts,
                               int* __restrict__ cnt, int* __restrict__ btok,
                               float* __restrict__ bw) {
  __shared__ int hist[NE];
  __shared__ int base[NE];
  int tid = threadIdx.x;
  if (tid < NE) hist[tid] = 0;
  __syncthreads();
  int t = blockIdx.x * 256 + tid;
  int2 s = sel[t]; float2 w = wts[t];
  int p0 = atomicAdd(&hist[s.x], 1);
  int p1 = atomicAdd(&hist[s.y], 1);
  __syncthreads();
  if (tid < NE) base[tid] = atomicAdd(&cnt[tid], hist[tid]);
  __syncthreads();
  int o0 = base[s.x] + p0;
  btok[s.x * T_TOKENS + o0] = t; bw[s.x * T_TOKENS + o0] = w.x;
  int o1 = base[s.y] + p1;
  btok[s.y * T_TOKENS + o1] = t; bw[s.y * T_TOKENS + o1] = w.y;
}

// ---------------- GEMM1: h = silu(Xe@W1) * (Xe@W3), gathered rows, fused ----------------
// Proven round-2 version: block tile 128(M) x 64(N), BK=64, 4 waves 2x2, dual B,
// T2 swizzle (linear LDS dest + pre-swizzled global col + XOR'd ds_read).
// 3D grid, nt fastest (A-tile sharing between consecutive blocks — round-8
// lesson: this beats B-panel-chunked orderings).
__global__ __launch_bounds__(256, 2) void gemm1_kernel(
    const unsigned short* __restrict__ xb, const unsigned short* __restrict__ w1t,
    const unsigned short* __restrict__ w3t, const int* __restrict__ cnt,
    const int* __restrict__ btok, const unsigned short* __restrict__ zbuf,
    unsigned short* __restrict__ h) {
  int e = blockIdx.z;
  int cn = cnt[e];
  int pc = (cn + 127) & ~127;
  int mt = blockIdx.y;
  if (mt * 128 >= pc) return;
  int hoff = 0;
#pragma unroll
  for (int i = 0; i < NE; i++) { int pi = (cnt[i] + 127) & ~127; if (i < e) hoff += pi; }
  int nt = blockIdx.x;

  __shared__ short8 At8[1024];  // [128][64] bf16
  __shared__ short8 B18[512];   // [64][64]
  __shared__ short8 B38[512];   // [64][64]

  int tid = threadIdx.x, wid = tid >> 6, lane = tid & 63;
  int m0 = mt * 128;

  int swzcol = ((lane & 7) ^ (lane >> 3)) * 8;

  const unsigned short* asrc[4];
#pragma unroll
  for (int rd = 0; rd < 4; rd++) {
    int row = (rd * 4 + wid) * 8 + (lane >> 3);
    int r = m0 + row;
    asrc[rd] = (r < cn) ? (xb + (size_t)btok[e * T_TOKENS + r] * DIM + swzcol)
                        : (zbuf + swzcol);
  }
  const unsigned short* b1s[2]; const unsigned short* b3s[2];
#pragma unroll
  for (int rd = 0; rd < 2; rd++) {
    int row = (rd * 4 + wid) * 8 + (lane >> 3);
    size_t o = ((size_t)e * HID + nt * 64 + row) * DIM + swzcol;
    b1s[rd] = w1t + o; b3s[rd] = w3t + o;
  }

  f32x4 zero = {0.f, 0.f, 0.f, 0.f};
  f32x4 acc1[4][2], acc3[4][2];
#pragma unroll
  for (int m = 0; m < 4; m++)
#pragma unroll
    for (int n = 0; n < 2; n++) { acc1[m][n] = zero; acc3[m][n] = zero; }

  int wr = wid >> 1, wc = wid & 1;
  const char* At = (const char*)At8;
  const char* B1 = (const char*)B18;
  const char* B3 = (const char*)B38;
  int lxor = (lane & 7) << 4;

  for (int kt = 0; kt < DIM / 64; kt++) {
    int ko = kt * 64;
#pragma unroll
    for (int rd = 0; rd < 4; rd++)
      gload16(asrc[rd] + ko, (char*)At8 + (rd * 4 + wid) * 1024);
#pragma unroll
    for (int rd = 0; rd < 2; rd++) {
      gload16(b1s[rd] + ko, (char*)B18 + (rd * 4 + wid) * 1024);
      gload16(b3s[rd] + ko, (char*)B38 + (rd * 4 + wid) * 1024);
    }
    __syncthreads();
#pragma unroll
    for (int ks = 0; ks < 2; ks++) {
      int cb = (ks * 64 + (lane >> 4) * 16) ^ lxor;
      short8 a[4], f1[2], f3[2];
#pragma unroll
      for (int m = 0; m < 4; m++)
        a[m] = *(const short8*)(At + (wr * 64 + m * 16 + (lane & 15)) * 128 + cb);
#pragma unroll
      for (int n = 0; n < 2; n++) {
        int rb = (wc * 32 + n * 16 + (lane & 15)) * 128 + cb;
        f1[n] = *(const short8*)(B1 + rb);
        f3[n] = *(const short8*)(B3 + rb);
      }
#pragma unroll
      for (int m = 0; m < 4; m++)
#pragma unroll
        for (int n = 0; n < 2; n++) {
          acc1[m][n] = __builtin_amdgcn_mfma_f32_16x16x32_bf16(a[m], f1[n], acc1[m][n], 0, 0, 0);
          acc3[m][n] = __builtin_amdgcn_mfma_f32_16x16x32_bf16(a[m], f3[n], acc3[m][n], 0, 0, 0);
        }
    }
    __syncthreads();
  }

#pragma unroll
  for (int m = 0; m < 4; m++)
#pragma unroll
    for (int n = 0; n < 2; n++) {
#pragma unroll
      for (int j = 0; j < 4; j++) {
        float s1 = acc1[m][n][j], s3 = acc3[m][n][j];
        float hv = s1 / (1.0f + __expf(-s1)) * s3;   // silu(s1)*s3
        int row = wr * 64 + m * 16 + (lane >> 4) * 4 + j;
        int col = nt * 64 + wc * 32 + n * 16 + (lane & 15);
        h[(size_t)(hoff + m0 + row) * HID + col] = f2bf(hv);
      }
    }
}

// ---------------- GEMM2: y = h @ W2, scale by gate weight, atomic combine ----------------
// Proven round-2 version: block tile 128(M) x 128(N), BK=64, 4 waves 2x2.
__global__ __launch_bounds__(256, 2) void gemm2_kernel(
    const unsigned short* __restrict__ h, const unsigned short* __restrict__ w2t,
    const int* __restrict__ cnt, const int* __restrict__ btok,
    const float* __restrict__ bw, float* __restrict__ out) {
  int e = blockIdx.z;
  int cn = cnt[e];
  int pc = (cn + 127) & ~127;
  int mt = blockIdx.y;
  if (mt * 128 >= pc) return;
  int hoff = 0;
#pragma unroll
  for (int i = 0; i < NE; i++) { int pi = (cnt[i] + 127) & ~127; if (i < e) hoff += pi; }
  int nt = blockIdx.x;

  __shared__ short8 At8[1024];  // [128][64]
  __shared__ short8 Bt8[1024];  // [128][64]

  int tid = threadIdx.x, wid = tid >> 6, lane = tid & 63;
  int m0 = mt * 128;

  int swzcol = ((lane & 7) ^ (lane >> 3)) * 8;

  const unsigned short* as[4]; const unsigned short* bs[4];
#pragma unroll
  for (int rd = 0; rd < 4; rd++) {
    int row = (rd * 4 + wid) * 8 + (lane >> 3);
    as[rd] = h + (size_t)(hoff + m0 + row) * HID + swzcol;
    bs[rd] = w2t + ((size_t)e * DIM + nt * 128 + row) * HID + swzcol;
  }

  f32x4 zero = {0.f, 0.f, 0.f, 0.f};
  f32x4 acc[4][4];
#pragma unroll
  for (int m = 0; m < 4; m++)
#pragma unroll
    for (int n = 0; n < 4; n++) acc[m][n] = zero;

  int wr = wid >> 1, wc = wid & 1;
  const char* At = (const char*)At8;
  const char* Bt = (const char*)Bt8;
  int lxor = (lane & 7) << 4;

  for (int kt = 0; kt < HID / 64; kt++) {
    int ko = kt * 64;
#pragma unroll
    for (int rd = 0; rd < 4; rd++) {
      gload16(as[rd] + ko, (char*)At8 + (rd * 4 + wid) * 1024);
      gload16(bs[rd] + ko, (char*)Bt8 + (rd * 4 + wid) * 1024);
    }
    __syncthreads();
#pragma unroll
    for (int ks = 0; ks < 2; ks++) {
      int cb = (ks * 64 + (lane >> 4) * 16) ^ lxor;
      short8 a[4], b[4];
#pragma unroll
      for (int m = 0; m < 4; m++)
        a[m] = *(const short8*)(At + (wr * 64 + m * 16 + (lane & 15)) * 128 + cb);
#pragma unroll
      for (int n = 0; n < 4; n++)
        b[n] = *(const short8*)(Bt + (wc * 64 + n * 16 + (lane & 15)) * 128 + cb);
#pragma unroll
      for (int m = 0; m < 4; m++)
#pragma unroll
        for (int n = 0; n < 4; n++)
          acc[m][n] = __builtin_amdgcn_mfma_f32_16x16x32_bf16(a[m], b[n], acc[m][n], 0, 0, 0);
    }
    __syncthreads();
  }

#pragma unroll
  for (int m = 0; m < 4; m++)
#pragma unroll
    for (int j = 0; j < 4; j++) {
      int r = m0 + wr * 64 + m * 16 + (lane >> 4) * 4 + j;
      if (r < cn) {
        int t = btok[e * T_TOKENS + r];
        float w = bw[e * T_TOKENS + r];
        size_t ob = (size_t)t * DIM + nt * 128 + wc * 64 + (lane & 15);
#pragma unroll
        for (int n = 0; n < 4; n++)
          atomicAdd(out + ob + n * 16, w * acc[m][n][j]);
      }
    }
}

extern "C" void kernel_launch(void* const* d_in, const int* in_sizes, int n_in,
                              void* d_out, int out_size, void* d_ws, size_t ws_size,
                              hipStream_t stream) {
  const float* x  = (const float*)d_in[0];
  const float* gw = (const float*)d_in[1];
  const float* w1 = (const float*)d_in[2];
  const float* w3 = (const float*)d_in[3];
  const float* w2 = (const float*)d_in[4];
  float* out = (float*)d_out;

  // workspace layout (~190 MiB total)
  char* ws = (char*)d_ws;
  unsigned short* W1T = (unsigned short*)ws;                      // [8][2048][1024] bf16
  unsigned short* W3T = W1T + (size_t)NE * HID * DIM;             // [8][2048][1024]
  unsigned short* W2T = W3T + (size_t)NE * HID * DIM;             // [8][1024][2048]
  unsigned short* XB  = W2T + (size_t)NE * DIM * HID;             // [8192][1024]
  unsigned short* H   = XB + (size_t)T_TOKENS * DIM;              // [17408][2048]
  int*   TOK = (int*)(H + (size_t)HCAP * HID);                    // [8][8192]
  float* BW  = (float*)(TOK + NE * T_TOKENS);                     // [8][8192]
  int*   CNT = (int*)(BW + NE * T_TOKENS);                        // [16]
  unsigned short* ZBUF = (unsigned short*)(CNT + 16);             // [1024] zeros
  int2*   SEL = (int2*)(ZBUF + 1024);                             // [8192]
  float2* WTS = (float2*)(SEL + T_TOKENS);                        // [8192]

  hipMemsetAsync(d_out, 0, (size_t)out_size * sizeof(float), stream);
  hipMemsetAsync(CNT, 0, 16 * sizeof(int) + 1024 * sizeof(unsigned short), stream);

  prep_kernel<<<14336, 256, 0, stream>>>(x, gw, w1, w3, w2, W1T, W3T, W2T, SEL, WTS, XB);
  scatter_kernel<<<T_TOKENS / 256, 256, 0, stream>>>(SEL, WTS, CNT, TOK, BW);
  gemm1_kernel<<<dim3(HID / 64, 64, NE), 256, 0, stream>>>(XB, W1T, W3T, CNT, TOK, ZBUF, H);
  gemm2_kernel<<<dim3(DIM / 128, 64, NE), 256, 0, stream>>>(H, W2T, CNT, TOK, BW, out);
}

// Round 10
// 337.314 us; speedup vs baseline: 1.1666x; 1.0596x over previous
//
#include <hip/hip_runtime.h>
#include <cstdint>
#include <cstddef>

// Problem constants
#define T_TOKENS 8192
#define DIM      1024
#define HID      2048
#define NE       8
#define HCAP     17408   // 16384 used rows + 8*128 max padding

typedef __attribute__((ext_vector_type(8))) short short8;
typedef __attribute__((ext_vector_type(4))) short short4v;
typedef __attribute__((ext_vector_type(4))) float f32x4;

__device__ __forceinline__ unsigned short f2bf(float f) {
  unsigned int u = __builtin_bit_cast(unsigned int, f);
  u += 0x7fffu + ((u >> 16) & 1u);   // RNE
  return (unsigned short)(u >> 16);
}

__device__ __forceinline__ float bf2f(unsigned short b) {
  unsigned int u = ((unsigned int)b) << 16;
  return __builtin_bit_cast(float, u);
}

__device__ __forceinline__ void gload16(const void* g, void* lds) {
  __builtin_amdgcn_global_load_lds((const __attribute__((address_space(1))) void*)g,
                                   (__attribute__((address_space(3))) void*)lds,
                                   16, 0, 0);
}

// ---------------- prep: fused {transcvt w1, w3, w2} + {gate} + {init} ----------------
// blocks [0,4096)        : w1 [E][K=1024][N=2048] -> W1T [E][N][K]
// blocks [4096,8192)     : w3 (same shape)
// blocks [8192,12288)    : w2 [E][K=2048][N=1024] -> W2T [E][N][K]
// blocks [12288,14336)   : gate (logits f64 + top-2 softmax + x->bf16)
// block PREP_GATE0 additionally zeroes CNT + ZBUF (consumed by later kernels)
#define PREP_GATE0 12288
__device__ __forceinline__ void transcvt_body(
    const float* __restrict__ in, unsigned short* __restrict__ out,
    int K, int N, int bx, int by, int e, float (*tile)[65], int tid) {
  int r  = tid >> 2;          // 0..63
  int c0 = (tid & 3) * 16;    // 0,16,32,48
  const float* src = in + ((size_t)e * K + by * 64 + r) * N + bx * 64 + c0;
#pragma unroll
  for (int j = 0; j < 4; j++) {
    float4 v = *(const float4*)(src + j * 4);
    tile[r][c0 + j * 4 + 0] = v.x; tile[r][c0 + j * 4 + 1] = v.y;
    tile[r][c0 + j * 4 + 2] = v.z; tile[r][c0 + j * 4 + 3] = v.w;
  }
  __syncthreads();
  short8 o0, o1;
#pragma unroll
  for (int j = 0; j < 8; j++) o0[j] = (short)f2bf(tile[c0 + j][r]);
#pragma unroll
  for (int j = 0; j < 8; j++) o1[j] = (short)f2bf(tile[c0 + 8 + j][r]);
  unsigned short* dst = out + ((size_t)e * N + bx * 64 + r) * K + by * 64 + c0;
  *(short8*)dst = o0;
  *(short8*)(dst + 8) = o1;
}

__global__ __launch_bounds__(256) void prep_kernel(
    const float* __restrict__ x, const float* __restrict__ gw,
    const float* __restrict__ w1, const float* __restrict__ w3,
    const float* __restrict__ w2,
    unsigned short* __restrict__ W1T, unsigned short* __restrict__ W3T,
    unsigned short* __restrict__ W2T,
    int2* __restrict__ sel, float2* __restrict__ wts,
    unsigned short* __restrict__ xb,
    int* __restrict__ cnt, unsigned short* __restrict__ zbuf) {
  __shared__ float tile[64][65];
  int bid = blockIdx.x, tid = threadIdx.x;

  if (bid < PREP_GATE0) {
    if (bid < 4096) {
      int t = bid;
      transcvt_body(w1, W1T, DIM, HID, t % 32, (t / 32) % 16, t / 512, tile, tid);
    } else if (bid < 8192) {
      int t = bid - 4096;
      transcvt_body(w3, W3T, DIM, HID, t % 32, (t / 32) % 16, t / 512, tile, tid);
    } else {
      int t = bid - 8192;
      transcvt_body(w2, W2T, HID, DIM, t % 16, (t / 16) % 32, t / 512, tile, tid);
    }
    return;
  }

  // ---- init (one block): zero CNT + ZBUF for this call ----
  if (bid == PREP_GATE0) {
    if (tid < 16) cnt[tid] = 0;
    short8 z = {0, 0, 0, 0, 0, 0, 0, 0};
    if (tid * 8 < 1024) *(short8*)(zbuf + tid * 8) = z;
  }

  // ---- gate: one wave per token ----
  int wid = tid >> 6, lane = tid & 63;
  int t = (bid - PREP_GATE0) * 4 + wid;
  const float* xr = x + (size_t)t * DIM;
  unsigned short* xo = xb + (size_t)t * DIM;
  double acc[NE];
#pragma unroll
  for (int e = 0; e < NE; e++) acc[e] = 0.0;
#pragma unroll
  for (int p = 0; p < 4; p++) {
    int idx = p * 256 + lane * 4;
    float4 xv = *(const float4*)(xr + idx);
    short4v o;
    o[0] = (short)f2bf(xv.x); o[1] = (short)f2bf(xv.y);
    o[2] = (short)f2bf(xv.z); o[3] = (short)f2bf(xv.w);
    *(short4v*)(xo + idx) = o;
#pragma unroll
    for (int e = 0; e < NE; e++) {
      float4 g = *(const float4*)(gw + e * DIM + idx);
      acc[e] += (double)xv.x * (double)g.x + (double)xv.y * (double)g.y
              + (double)xv.z * (double)g.z + (double)xv.w * (double)g.w;
    }
  }
#pragma unroll
  for (int e = 0; e < NE; e++) {
    double v = acc[e];
#pragma unroll
    for (int off = 32; off > 0; off >>= 1) v += __shfl_xor(v, off);
    acc[e] = v;
  }
  if (lane == 0) {
    float l[NE];
#pragma unroll
    for (int e = 0; e < NE; e++) l[e] = (float)acc[e];
    int i0 = 0; float v0 = l[0];
#pragma unroll
    for (int e = 1; e < NE; e++) if (l[e] > v0) { v0 = l[e]; i0 = e; }
    int i1 = -1; float v1 = -3.4e38f;
#pragma unroll
    for (int e = 0; e < NE; e++) if (e != i0 && l[e] > v1) { v1 = l[e]; i1 = e; }
    float ew = __expf(v1 - v0);          // v1 <= v0, stable
    float w0 = 1.0f / (1.0f + ew);
    float w1v = ew / (1.0f + ew);
    sel[t] = make_int2(i0, i1);
    wts[t] = make_float2(w0, w1v);
  }
}

// ------- gate phase B: block-aggregated bucket scatter (+ inverse position map) -------
__global__ void scatter_kernel(const int2* __restrict__ sel, const float2* __restrict__ wts,
                               int* __restrict__ cnt, int* __restrict__ btok,
                               float* __restrict__ bw, int2* __restrict__ pos) {
  __shared__ int hist[NE];
  __shared__ int base[NE];
  int tid = threadIdx.x;
  if (tid < NE) hist[tid] = 0;
  __syncthreads();
  int t = blockIdx.x * 256 + tid;
  int2 s = sel[t]; float2 w = wts[t];
  int p0 = atomicAdd(&hist[s.x], 1);
  int p1 = atomicAdd(&hist[s.y], 1);
  __syncthreads();
  if (tid < NE) base[tid] = atomicAdd(&cnt[tid], hist[tid]);
  __syncthreads();
  int o0 = base[s.x] + p0;
  btok[s.x * T_TOKENS + o0] = t; bw[s.x * T_TOKENS + o0] = w.x;
  int o1 = base[s.y] + p1;
  btok[s.y * T_TOKENS + o1] = t; bw[s.y * T_TOKENS + o1] = w.y;
  pos[t] = make_int2(o0, o1);
}

// ---------------- GEMM1: h = silu(Xe@W1) * (Xe@W3), gathered rows, fused ----------------
// Proven round-2 version: block tile 128(M) x 64(N), BK=64, 4 waves 2x2, dual B,
// T2 swizzle (linear LDS dest + pre-swizzled global col + XOR'd ds_read).
__global__ __launch_bounds__(256, 2) void gemm1_kernel(
    const unsigned short* __restrict__ xb, const unsigned short* __restrict__ w1t,
    const unsigned short* __restrict__ w3t, const int* __restrict__ cnt,
    const int* __restrict__ btok, const unsigned short* __restrict__ zbuf,
    unsigned short* __restrict__ h) {
  int e = blockIdx.z;
  int cn = cnt[e];
  int pc = (cn + 127) & ~127;
  int mt = blockIdx.y;
  if (mt * 128 >= pc) return;
  int hoff = 0;
#pragma unroll
  for (int i = 0; i < NE; i++) { int pi = (cnt[i] + 127) & ~127; if (i < e) hoff += pi; }
  int nt = blockIdx.x;

  __shared__ short8 At8[1024];  // [128][64] bf16
  __shared__ short8 B18[512];   // [64][64]
  __shared__ short8 B38[512];   // [64][64]

  int tid = threadIdx.x, wid = tid >> 6, lane = tid & 63;
  int m0 = mt * 128;

  int swzcol = ((lane & 7) ^ (lane >> 3)) * 8;

  const unsigned short* asrc[4];
#pragma unroll
  for (int rd = 0; rd < 4; rd++) {
    int row = (rd * 4 + wid) * 8 + (lane >> 3);
    int r = m0 + row;
    asrc[rd] = (r < cn) ? (xb + (size_t)btok[e * T_TOKENS + r] * DIM + swzcol)
                        : (zbuf + swzcol);
  }
  const unsigned short* b1s[2]; const unsigned short* b3s[2];
#pragma unroll
  for (int rd = 0; rd < 2; rd++) {
    int row = (rd * 4 + wid) * 8 + (lane >> 3);
    size_t o = ((size_t)e * HID + nt * 64 + row) * DIM + swzcol;
    b1s[rd] = w1t + o; b3s[rd] = w3t + o;
  }

  f32x4 zero = {0.f, 0.f, 0.f, 0.f};
  f32x4 acc1[4][2], acc3[4][2];
#pragma unroll
  for (int m = 0; m < 4; m++)
#pragma unroll
    for (int n = 0; n < 2; n++) { acc1[m][n] = zero; acc3[m][n] = zero; }

  int wr = wid >> 1, wc = wid & 1;
  const char* At = (const char*)At8;
  const char* B1 = (const char*)B18;
  const char* B3 = (const char*)B38;
  int lxor = (lane & 7) << 4;

  for (int kt = 0; kt < DIM / 64; kt++) {
    int ko = kt * 64;
#pragma unroll
    for (int rd = 0; rd < 4; rd++)
      gload16(asrc[rd] + ko, (char*)At8 + (rd * 4 + wid) * 1024);
#pragma unroll
    for (int rd = 0; rd < 2; rd++) {
      gload16(b1s[rd] + ko, (char*)B18 + (rd * 4 + wid) * 1024);
      gload16(b3s[rd] + ko, (char*)B38 + (rd * 4 + wid) * 1024);
    }
    __syncthreads();
#pragma unroll
    for (int ks = 0; ks < 2; ks++) {
      int cb = (ks * 64 + (lane >> 4) * 16) ^ lxor;
      short8 a[4], f1[2], f3[2];
#pragma unroll
      for (int m = 0; m < 4; m++)
        a[m] = *(const short8*)(At + (wr * 64 + m * 16 + (lane & 15)) * 128 + cb);
#pragma unroll
      for (int n = 0; n < 2; n++) {
        int rb = (wc * 32 + n * 16 + (lane & 15)) * 128 + cb;
        f1[n] = *(const short8*)(B1 + rb);
        f3[n] = *(const short8*)(B3 + rb);
      }
#pragma unroll
      for (int m = 0; m < 4; m++)
#pragma unroll
        for (int n = 0; n < 2; n++) {
          acc1[m][n] = __builtin_amdgcn_mfma_f32_16x16x32_bf16(a[m], f1[n], acc1[m][n], 0, 0, 0);
          acc3[m][n] = __builtin_amdgcn_mfma_f32_16x16x32_bf16(a[m], f3[n], acc3[m][n], 0, 0, 0);
        }
    }
    __syncthreads();
  }

#pragma unroll
  for (int m = 0; m < 4; m++)
#pragma unroll
    for (int n = 0; n < 2; n++) {
#pragma unroll
      for (int j = 0; j < 4; j++) {
        float s1 = acc1[m][n][j], s3 = acc3[m][n][j];
        float hv = s1 / (1.0f + __expf(-s1)) * s3;   // silu(s1)*s3
        int row = wr * 64 + m * 16 + (lane >> 4) * 4 + j;
        int col = nt * 64 + wc * 32 + n * 16 + (lane & 15);
        h[(size_t)(hoff + m0 + row) * HID + col] = f2bf(hv);
      }
    }
}

// ---------------- GEMM2: y = w * (h @ W2), NON-ATOMIC bf16 partial store ----------------
// Proven round-2 inner structure: block tile 128(M) x 128(N), BK=64, 4 waves 2x2.
// Epilogue stores scaled partial rows into Y (H-row indexed); combine adds pairs.
__global__ __launch_bounds__(256, 2) void gemm2_kernel(
    const unsigned short* __restrict__ h, const unsigned short* __restrict__ w2t,
    const int* __restrict__ cnt, const float* __restrict__ bw,
    unsigned short* __restrict__ Y) {
  int e = blockIdx.z;
  int cn = cnt[e];
  int pc = (cn + 127) & ~127;
  int mt = blockIdx.y;
  if (mt * 128 >= pc) return;
  int hoff = 0;
#pragma unroll
  for (int i = 0; i < NE; i++) { int pi = (cnt[i] + 127) & ~127; if (i < e) hoff += pi; }
  int nt = blockIdx.x;

  __shared__ short8 At8[1024];  // [128][64]
  __shared__ short8 Bt8[1024];  // [128][64]

  int tid = threadIdx.x, wid = tid >> 6, lane = tid & 63;
  int m0 = mt * 128;

  int swzcol = ((lane & 7) ^ (lane >> 3)) * 8;

  const unsigned short* as[4]; const unsigned short* bs[4];
#pragma unroll
  for (int rd = 0; rd < 4; rd++) {
    int row = (rd * 4 + wid) * 8 + (lane >> 3);
    as[rd] = h + (size_t)(hoff + m0 + row) * HID + swzcol;
    bs[rd] = w2t + ((size_t)e * DIM + nt * 128 + row) * HID + swzcol;
  }

  f32x4 zero = {0.f, 0.f, 0.f, 0.f};
  f32x4 acc[4][4];
#pragma unroll
  for (int m = 0; m < 4; m++)
#pragma unroll
    for (int n = 0; n < 4; n++) acc[m][n] = zero;

  int wr = wid >> 1, wc = wid & 1;
  const char* At = (const char*)At8;
  const char* Bt = (const char*)Bt8;
  int lxor = (lane & 7) << 4;

  for (int kt = 0; kt < HID / 64; kt++) {
    int ko = kt * 64;
#pragma unroll
    for (int rd = 0; rd < 4; rd++) {
      gload16(as[rd] + ko, (char*)At8 + (rd * 4 + wid) * 1024);
      gload16(bs[rd] + ko, (char*)Bt8 + (rd * 4 + wid) * 1024);
    }
    __syncthreads();
#pragma unroll
    for (int ks = 0; ks < 2; ks++) {
      int cb = (ks * 64 + (lane >> 4) * 16) ^ lxor;
      short8 a[4], b[4];
#pragma unroll
      for (int m = 0; m < 4; m++)
        a[m] = *(const short8*)(At + (wr * 64 + m * 16 + (lane & 15)) * 128 + cb);
#pragma unroll
      for (int n = 0; n < 4; n++)
        b[n] = *(const short8*)(Bt + (wc * 64 + n * 16 + (lane & 15)) * 128 + cb);
#pragma unroll
      for (int m = 0; m < 4; m++)
#pragma unroll
        for (int n = 0; n < 4; n++)
          acc[m][n] = __builtin_amdgcn_mfma_f32_16x16x32_bf16(a[m], b[n], acc[m][n], 0, 0, 0);
    }
    __syncthreads();
  }

#pragma unroll
  for (int m = 0; m < 4; m++)
#pragma unroll
    for (int j = 0; j < 4; j++) {
      int r = m0 + wr * 64 + m * 16 + (lane >> 4) * 4 + j;
      if (r < cn) {
        float w = bw[e * T_TOKENS + r];
        size_t yb = (size_t)(hoff + r) * DIM + nt * 128 + wc * 64 + (lane & 15);
#pragma unroll
        for (int n = 0; n < 4; n++)
          Y[yb + n * 16] = f2bf(w * acc[m][n][j]);
      }
    }
}

// ---------------- combine: out[t] = Y[g0(t)] + Y[g1(t)] ----------------
// 256 thr = 2 tokens/block (128 thr x 8 elems each)
__global__ __launch_bounds__(256) void combine_kernel(
    const unsigned short* __restrict__ Y, const int2* __restrict__ sel,
    const int2* __restrict__ pos, const int* __restrict__ cnt,
    float* __restrict__ out) {
  int hoffs[NE + 1];
  hoffs[0] = 0;
#pragma unroll
  for (int i = 0; i < NE; i++) hoffs[i + 1] = hoffs[i] + ((cnt[i] + 127) & ~127);

  int tid = threadIdx.x;
  int t = blockIdx.x * 2 + (tid >> 7);
  int d0 = (tid & 127) * 8;
  int2 s = sel[t];
  int2 p = pos[t];
  size_t g0 = (size_t)(hoffs[s.x] + p.x) * DIM + d0;
  size_t g1 = (size_t)(hoffs[s.y] + p.y) * DIM + d0;
  short8 a = *(const short8*)(Y + g0);
  short8 b = *(const short8*)(Y + g1);
  float* o = out + (size_t)t * DIM + d0;
  f32x4 lo, hi;
#pragma unroll
  for (int j = 0; j < 4; j++) lo[j] = bf2f((unsigned short)a[j]) + bf2f((unsigned short)b[j]);
#pragma unroll
  for (int j = 0; j < 4; j++) hi[j] = bf2f((unsigned short)a[4 + j]) + bf2f((unsigned short)b[4 + j]);
  *(f32x4*)o = lo;
  *(f32x4*)(o + 4) = hi;
}

extern "C" void kernel_launch(void* const* d_in, const int* in_sizes, int n_in,
                              void* d_out, int out_size, void* d_ws, size_t ws_size,
                              hipStream_t stream) {
  const float* x  = (const float*)d_in[0];
  const float* gw = (const float*)d_in[1];
  const float* w1 = (const float*)d_in[2];
  const float* w3 = (const float*)d_in[3];
  const float* w2 = (const float*)d_in[4];
  float* out = (float*)d_out;

  // workspace layout (~190 MiB total)
  char* ws = (char*)d_ws;
  unsigned short* W1T = (unsigned short*)ws;                      // [8][2048][1024] bf16
  unsigned short* W3T = W1T + (size_t)NE * HID * DIM;             // [8][2048][1024]
  unsigned short* W2T = W3T + (size_t)NE * HID * DIM;             // [8][1024][2048]
  unsigned short* XB  = W2T + (size_t)NE * DIM * HID;             // [8192][1024]
  unsigned short* H   = XB + (size_t)T_TOKENS * DIM;              // [17408][2048]
  int*   TOK = (int*)(H + (size_t)HCAP * HID);                    // [8][8192]
  float* BW  = (float*)(TOK + NE * T_TOKENS);                     // [8][8192]
  int*   CNT = (int*)(BW + NE * T_TOKENS);                        // [16]
  unsigned short* ZBUF = (unsigned short*)(CNT + 16);             // [1024] zeros
  int2*   SEL = (int2*)(ZBUF + 1024);                             // [8192]
  float2* WTS = (float2*)(SEL + T_TOKENS);                        // [8192]
  int2*   POS = (int2*)(WTS + T_TOKENS);                          // [8192]
  // Y aliases W1T/W3T (dead after gemm1): [HCAP][1024] bf16 = 34 MB
  unsigned short* Y = W1T;

  prep_kernel<<<14336, 256, 0, stream>>>(x, gw, w1, w3, w2, W1T, W3T, W2T,
                                         SEL, WTS, XB, CNT, ZBUF);
  scatter_kernel<<<T_TOKENS / 256, 256, 0, stream>>>(SEL, WTS, CNT, TOK, BW, POS);
  gemm1_kernel<<<dim3(HID / 64, 64, NE), 256, 0, stream>>>(XB, W1T, W3T, CNT, TOK, ZBUF, H);
  gemm2_kernel<<<dim3(DIM / 128, 64, NE), 256, 0, stream>>>(H, W2T, CNT, BW, Y);
  combine_kernel<<<T_TOKENS / 2, 256, 0, stream>>>(Y, SEL, POS, CNT, out);
}

// Round 12
// 311.219 us; speedup vs baseline: 1.2644x; 1.0838x over previous
//
#include <hip/hip_runtime.h>
#include <cstdint>
#include <cstddef>

// Problem constants
#define T_TOKENS 8192
#define DIM      1024
#define HID      2048
#define NE       8
#define HCAP     17408   // 16384 used rows + 8*128 max padding

// Y partial buffer: one K-half = (2*T_TOKENS) rows x DIM cols (compact cn-prefix rows)
#define YHALF ((size_t)(2 * T_TOKENS) * DIM)   // 16,777,216 elements = 32 MiB bf16

typedef __attribute__((ext_vector_type(8))) short short8;
typedef __attribute__((ext_vector_type(4))) short short4v;
typedef __attribute__((ext_vector_type(4))) float f32x4;

__device__ __forceinline__ unsigned short f2bf(float f) {
  unsigned int u = __builtin_bit_cast(unsigned int, f);
  u += 0x7fffu + ((u >> 16) & 1u);   // RNE
  return (unsigned short)(u >> 16);
}

__device__ __forceinline__ float bf2f(unsigned short b) {
  unsigned int u = ((unsigned int)b) << 16;
  return __builtin_bit_cast(float, u);
}

__device__ __forceinline__ void gload16(const void* g, void* lds) {
  __builtin_amdgcn_global_load_lds((const __attribute__((address_space(1))) void*)g,
                                   (__attribute__((address_space(3))) void*)lds,
                                   16, 0, 0);
}

// ---------------- prep: fused {transcvt w1, w3, w2} + {gate} + {init} ----------------
#define PREP_GATE0 12288
__device__ __forceinline__ void transcvt_body(
    const float* __restrict__ in, unsigned short* __restrict__ out,
    int K, int N, int bx, int by, int e, float (*tile)[65], int tid) {
  int r  = tid >> 2;          // 0..63
  int c0 = (tid & 3) * 16;    // 0,16,32,48
  const float* src = in + ((size_t)e * K + by * 64 + r) * N + bx * 64 + c0;
#pragma unroll
  for (int j = 0; j < 4; j++) {
    float4 v = *(const float4*)(src + j * 4);
    tile[r][c0 + j * 4 + 0] = v.x; tile[r][c0 + j * 4 + 1] = v.y;
    tile[r][c0 + j * 4 + 2] = v.z; tile[r][c0 + j * 4 + 3] = v.w;
  }
  __syncthreads();
  short8 o0, o1;
#pragma unroll
  for (int j = 0; j < 8; j++) o0[j] = (short)f2bf(tile[c0 + j][r]);
#pragma unroll
  for (int j = 0; j < 8; j++) o1[j] = (short)f2bf(tile[c0 + 8 + j][r]);
  unsigned short* dst = out + ((size_t)e * N + bx * 64 + r) * K + by * 64 + c0;
  *(short8*)dst = o0;
  *(short8*)(dst + 8) = o1;
}

__global__ __launch_bounds__(256) void prep_kernel(
    const float* __restrict__ x, const float* __restrict__ gw,
    const float* __restrict__ w1, const float* __restrict__ w3,
    const float* __restrict__ w2,
    unsigned short* __restrict__ W1T, unsigned short* __restrict__ W3T,
    unsigned short* __restrict__ W2T,
    int2* __restrict__ sel, float2* __restrict__ wts,
    unsigned short* __restrict__ xb,
    int* __restrict__ cnt, unsigned short* __restrict__ zbuf) {
  __shared__ float tile[64][65];
  int bid = blockIdx.x, tid = threadIdx.x;

  if (bid < PREP_GATE0) {
    if (bid < 4096) {
      int t = bid;
      transcvt_body(w1, W1T, DIM, HID, t % 32, (t / 32) % 16, t / 512, tile, tid);
    } else if (bid < 8192) {
      int t = bid - 4096;
      transcvt_body(w3, W3T, DIM, HID, t % 32, (t / 32) % 16, t / 512, tile, tid);
    } else {
      int t = bid - 8192;
      transcvt_body(w2, W2T, HID, DIM, t % 16, (t / 16) % 32, t / 512, tile, tid);
    }
    return;
  }

  // ---- init (one block): zero CNT + ZBUF for this call ----
  if (bid == PREP_GATE0) {
    if (tid < 16) cnt[tid] = 0;
    short8 z = {0, 0, 0, 0, 0, 0, 0, 0};
    if (tid * 8 < 1024) *(short8*)(zbuf + tid * 8) = z;
  }

  // ---- gate: one wave per token ----
  int wid = tid >> 6, lane = tid & 63;
  int t = (bid - PREP_GATE0) * 4 + wid;
  const float* xr = x + (size_t)t * DIM;
  unsigned short* xo = xb + (size_t)t * DIM;
  double acc[NE];
#pragma unroll
  for (int e = 0; e < NE; e++) acc[e] = 0.0;
#pragma unroll
  for (int p = 0; p < 4; p++) {
    int idx = p * 256 + lane * 4;
    float4 xv = *(const float4*)(xr + idx);
    short4v o;
    o[0] = (short)f2bf(xv.x); o[1] = (short)f2bf(xv.y);
    o[2] = (short)f2bf(xv.z); o[3] = (short)f2bf(xv.w);
    *(short4v*)(xo + idx) = o;
#pragma unroll
    for (int e = 0; e < NE; e++) {
      float4 g = *(const float4*)(gw + e * DIM + idx);
      acc[e] += (double)xv.x * (double)g.x + (double)xv.y * (double)g.y
              + (double)xv.z * (double)g.z + (double)xv.w * (double)g.w;
    }
  }
#pragma unroll
  for (int e = 0; e < NE; e++) {
    double v = acc[e];
#pragma unroll
    for (int off = 32; off > 0; off >>= 1) v += __shfl_xor(v, off);
    acc[e] = v;
  }
  if (lane == 0) {
    float l[NE];
#pragma unroll
    for (int e = 0; e < NE; e++) l[e] = (float)acc[e];
    int i0 = 0; float v0 = l[0];
#pragma unroll
    for (int e = 1; e < NE; e++) if (l[e] > v0) { v0 = l[e]; i0 = e; }
    int i1 = -1; float v1 = -3.4e38f;
#pragma unroll
    for (int e = 0; e < NE; e++) if (e != i0 && l[e] > v1) { v1 = l[e]; i1 = e; }
    float ew = __expf(v1 - v0);          // v1 <= v0, stable
    float w0 = 1.0f / (1.0f + ew);
    float w1v = ew / (1.0f + ew);
    sel[t] = make_int2(i0, i1);
    wts[t] = make_float2(w0, w1v);
  }
}

// ------- gate phase B: block-aggregated bucket scatter (+ inverse position map) -------
__global__ void scatter_kernel(const int2* __restrict__ sel, const float2* __restrict__ wts,
                               int* __restrict__ cnt, int* __restrict__ btok,
                               float* __restrict__ bw, int2* __restrict__ pos) {
  __shared__ int hist[NE];
  __shared__ int base[NE];
  int tid = threadIdx.x;
  if (tid < NE) hist[tid] = 0;
  __syncthreads();
  int t = blockIdx.x * 256 + tid;
  int2 s = sel[t]; float2 w = wts[t];
  int p0 = atomicAdd(&hist[s.x], 1);
  int p1 = atomicAdd(&hist[s.y], 1);
  __syncthreads();
  if (tid < NE) base[tid] = atomicAdd(&cnt[tid], hist[tid]);
  __syncthreads();
  int o0 = base[s.x] + p0;
  btok[s.x * T_TOKENS + o0] = t; bw[s.x * T_TOKENS + o0] = w.x;
  int o1 = base[s.y] + p1;
  btok[s.y * T_TOKENS + o1] = t; bw[s.y * T_TOKENS + o1] = w.y;
  pos[t] = make_int2(o0, o1);
}

// ---------------- GEMM1: h = silu(Xe@W1) * (Xe@W3), gathered rows, fused ----------------
// Proven round-2 version: block tile 128(M) x 64(N), BK=64, 4 waves 2x2, dual B,
// T2 swizzle (linear LDS dest + pre-swizzled global col + XOR'd ds_read).
__global__ __launch_bounds__(256, 2) void gemm1_kernel(
    const unsigned short* __restrict__ xb, const unsigned short* __restrict__ w1t,
    const unsigned short* __restrict__ w3t, const int* __restrict__ cnt,
    const int* __restrict__ btok, const unsigned short* __restrict__ zbuf,
    unsigned short* __restrict__ h) {
  int e = blockIdx.z;
  int cn = cnt[e];
  int pc = (cn + 127) & ~127;
  int mt = blockIdx.y;
  if (mt * 128 >= pc) return;
  int hoff = 0;
#pragma unroll
  for (int i = 0; i < NE; i++) { int pi = (cnt[i] + 127) & ~127; if (i < e) hoff += pi; }
  int nt = blockIdx.x;

  __shared__ short8 At8[1024];  // [128][64] bf16
  __shared__ short8 B18[512];   // [64][64]
  __shared__ short8 B38[512];   // [64][64]

  int tid = threadIdx.x, wid = tid >> 6, lane = tid & 63;
  int m0 = mt * 128;

  int swzcol = ((lane & 7) ^ (lane >> 3)) * 8;

  const unsigned short* asrc[4];
#pragma unroll
  for (int rd = 0; rd < 4; rd++) {
    int row = (rd * 4 + wid) * 8 + (lane >> 3);
    int r = m0 + row;
    asrc[rd] = (r < cn) ? (xb + (size_t)btok[e * T_TOKENS + r] * DIM + swzcol)
                        : (zbuf + swzcol);
  }
  const unsigned short* b1s[2]; const unsigned short* b3s[2];
#pragma unroll
  for (int rd = 0; rd < 2; rd++) {
    int row = (rd * 4 + wid) * 8 + (lane >> 3);
    size_t o = ((size_t)e * HID + nt * 64 + row) * DIM + swzcol;
    b1s[rd] = w1t + o; b3s[rd] = w3t + o;
  }

  f32x4 zero = {0.f, 0.f, 0.f, 0.f};
  f32x4 acc1[4][2], acc3[4][2];
#pragma unroll
  for (int m = 0; m < 4; m++)
#pragma unroll
    for (int n = 0; n < 2; n++) { acc1[m][n] = zero; acc3[m][n] = zero; }

  int wr = wid >> 1, wc = wid & 1;
  const char* At = (const char*)At8;
  const char* B1 = (const char*)B18;
  const char* B3 = (const char*)B38;
  int lxor = (lane & 7) << 4;

  for (int kt = 0; kt < DIM / 64; kt++) {
    int ko = kt * 64;
#pragma unroll
    for (int rd = 0; rd < 4; rd++)
      gload16(asrc[rd] + ko, (char*)At8 + (rd * 4 + wid) * 1024);
#pragma unroll
    for (int rd = 0; rd < 2; rd++) {
      gload16(b1s[rd] + ko, (char*)B18 + (rd * 4 + wid) * 1024);
      gload16(b3s[rd] + ko, (char*)B38 + (rd * 4 + wid) * 1024);
    }
    __syncthreads();
#pragma unroll
    for (int ks = 0; ks < 2; ks++) {
      int cb = (ks * 64 + (lane >> 4) * 16) ^ lxor;
      short8 a[4], f1[2], f3[2];
#pragma unroll
      for (int m = 0; m < 4; m++)
        a[m] = *(const short8*)(At + (wr * 64 + m * 16 + (lane & 15)) * 128 + cb);
#pragma unroll
      for (int n = 0; n < 2; n++) {
        int rb = (wc * 32 + n * 16 + (lane & 15)) * 128 + cb;
        f1[n] = *(const short8*)(B1 + rb);
        f3[n] = *(const short8*)(B3 + rb);
      }
#pragma unroll
      for (int m = 0; m < 4; m++)
#pragma unroll
        for (int n = 0; n < 2; n++) {
          acc1[m][n] = __builtin_amdgcn_mfma_f32_16x16x32_bf16(a[m], f1[n], acc1[m][n], 0, 0, 0);
          acc3[m][n] = __builtin_amdgcn_mfma_f32_16x16x32_bf16(a[m], f3[n], acc3[m][n], 0, 0, 0);
        }
    }
    __syncthreads();
  }

#pragma unroll
  for (int m = 0; m < 4; m++)
#pragma unroll
    for (int n = 0; n < 2; n++) {
#pragma unroll
      for (int j = 0; j < 4; j++) {
        float s1 = acc1[m][n][j], s3 = acc3[m][n][j];
        float hv = s1 / (1.0f + __expf(-s1)) * s3;   // silu(s1)*s3
        int row = wr * 64 + m * 16 + (lane >> 4) * 4 + j;
        int col = nt * 64 + wc * 32 + n * 16 + (lane & 15);
        h[(size_t)(hoff + m0 + row) * HID + col] = f2bf(hv);
      }
    }
}

// ------- GEMM2: y_partial = w * (h @ W2[K-half]), K-split 2, non-atomic bf16 -------
// Proven round-2 inner structure; blockIdx.x = nt*2 + kh. Each block does 16 K-steps.
// Output: Y[kh] at compact cn-prefix rows (no padding; sum(cn) == 2*T_TOKENS).
__global__ __launch_bounds__(256, 2) void gemm2_kernel(
    const unsigned short* __restrict__ h, const unsigned short* __restrict__ w2t,
    const int* __restrict__ cnt, const float* __restrict__ bw,
    unsigned short* __restrict__ Y) {
  int e = blockIdx.z;
  int cn = cnt[e];
  int pc = (cn + 127) & ~127;
  int mt = blockIdx.y;
  if (mt * 128 >= pc) return;
  int hoff = 0, coff = 0;
#pragma unroll
  for (int i = 0; i < NE; i++) {
    int ci = cnt[i];
    if (i < e) { hoff += (ci + 127) & ~127; coff += ci; }
  }
  int nt = blockIdx.x >> 1;
  int kh = blockIdx.x & 1;
  unsigned short* Yk = Y + (size_t)kh * YHALF;

  __shared__ short8 At8[1024];  // [128][64]
  __shared__ short8 Bt8[1024];  // [128][64]

  int tid = threadIdx.x, wid = tid >> 6, lane = tid & 63;
  int m0 = mt * 128;
  int k0 = kh * (HID / 2);     // element offset of this K-half

  int swzcol = ((lane & 7) ^ (lane >> 3)) * 8;

  const unsigned short* as[4]; const unsigned short* bs[4];
#pragma unroll
  for (int rd = 0; rd < 4; rd++) {
    int row = (rd * 4 + wid) * 8 + (lane >> 3);
    as[rd] = h + (size_t)(hoff + m0 + row) * HID + k0 + swzcol;
    bs[rd] = w2t + ((size_t)e * DIM + nt * 128 + row) * HID + k0 + swzcol;
  }

  f32x4 zero = {0.f, 0.f, 0.f, 0.f};
  f32x4 acc[4][4];
#pragma unroll
  for (int m = 0; m < 4; m++)
#pragma unroll
    for (int n = 0; n < 4; n++) acc[m][n] = zero;

  int wr = wid >> 1, wc = wid & 1;
  const char* At = (const char*)At8;
  const char* Bt = (const char*)Bt8;
  int lxor = (lane & 7) << 4;

  for (int kt = 0; kt < HID / 128; kt++) {   // 16 K-steps (half of 32)
    int ko = kt * 64;
#pragma unroll
    for (int rd = 0; rd < 4; rd++) {
      gload16(as[rd] + ko, (char*)At8 + (rd * 4 + wid) * 1024);
      gload16(bs[rd] + ko, (char*)Bt8 + (rd * 4 + wid) * 1024);
    }
    __syncthreads();
#pragma unroll
    for (int ks = 0; ks < 2; ks++) {
      int cb = (ks * 64 + (lane >> 4) * 16) ^ lxor;
      short8 a[4], b[4];
#pragma unroll
      for (int m = 0; m < 4; m++)
        a[m] = *(const short8*)(At + (wr * 64 + m * 16 + (lane & 15)) * 128 + cb);
#pragma unroll
      for (int n = 0; n < 4; n++)
        b[n] = *(const short8*)(Bt + (wc * 64 + n * 16 + (lane & 15)) * 128 + cb);
#pragma unroll
      for (int m = 0; m < 4; m++)
#pragma unroll
        for (int n = 0; n < 4; n++)
          acc[m][n] = __builtin_amdgcn_mfma_f32_16x16x32_bf16(a[m], b[n], acc[m][n], 0, 0, 0);
    }
    __syncthreads();
  }

#pragma unroll
  for (int m = 0; m < 4; m++)
#pragma unroll
    for (int j = 0; j < 4; j++) {
      int r = m0 + wr * 64 + m * 16 + (lane >> 4) * 4 + j;
      if (r < cn) {
        float w = bw[e * T_TOKENS + r];
        size_t yb = (size_t)(coff + r) * DIM + nt * 128 + wc * 64 + (lane & 15);
#pragma unroll
        for (int n = 0; n < 4; n++)
          Yk[yb + n * 16] = f2bf(w * acc[m][n][j]);
      }
    }
}

// ------- combine: out[t] = Y0[g0]+Y1[g0] + Y0[g1]+Y1[g1] (2 experts x 2 K-halves) -------
__global__ __launch_bounds__(256) void combine_kernel(
    const unsigned short* __restrict__ Y, const int2* __restrict__ sel,
    const int2* __restrict__ pos, const int* __restrict__ cnt,
    float* __restrict__ out) {
  int coffs[NE + 1];
  coffs[0] = 0;
#pragma unroll
  for (int i = 0; i < NE; i++) coffs[i + 1] = coffs[i] + cnt[i];

  const unsigned short* Y1 = Y + YHALF;  // second K-half

  int tid = threadIdx.x;
  int t = blockIdx.x * 2 + (tid >> 7);
  int d0 = (tid & 127) * 8;
  int2 s = sel[t];
  int2 p = pos[t];
  size_t g0 = (size_t)(coffs[s.x] + p.x) * DIM + d0;
  size_t g1 = (size_t)(coffs[s.y] + p.y) * DIM + d0;
  short8 a0 = *(const short8*)(Y + g0);
  short8 a1 = *(const short8*)(Y1 + g0);
  short8 b0 = *(const short8*)(Y + g1);
  short8 b1 = *(const short8*)(Y1 + g1);
  float* o = out + (size_t)t * DIM + d0;
  f32x4 lo, hi;
#pragma unroll
  for (int j = 0; j < 4; j++)
    lo[j] = bf2f((unsigned short)a0[j]) + bf2f((unsigned short)a1[j])
          + bf2f((unsigned short)b0[j]) + bf2f((unsigned short)b1[j]);
#pragma unroll
  for (int j = 0; j < 4; j++)
    hi[j] = bf2f((unsigned short)a0[4 + j]) + bf2f((unsigned short)a1[4 + j])
          + bf2f((unsigned short)b0[4 + j]) + bf2f((unsigned short)b1[4 + j]);
  *(f32x4*)o = lo;
  *(f32x4*)(o + 4) = hi;
}

extern "C" void kernel_launch(void* const* d_in, const int* in_sizes, int n_in,
                              void* d_out, int out_size, void* d_ws, size_t ws_size,
                              hipStream_t stream) {
  const float* x  = (const float*)d_in[0];
  const float* gw = (const float*)d_in[1];
  const float* w1 = (const float*)d_in[2];
  const float* w3 = (const float*)d_in[3];
  const float* w2 = (const float*)d_in[4];
  float* out = (float*)d_out;

  // workspace layout (~190 MiB total)
  char* ws = (char*)d_ws;
  unsigned short* W1T = (unsigned short*)ws;                      // [8][2048][1024] bf16
  unsigned short* W3T = W1T + (size_t)NE * HID * DIM;             // [8][2048][1024]
  unsigned short* W2T = W3T + (size_t)NE * HID * DIM;             // [8][1024][2048]
  unsigned short* XB  = W2T + (size_t)NE * DIM * HID;             // [8192][1024]
  unsigned short* H   = XB + (size_t)T_TOKENS * DIM;              // [17408][2048]
  int*   TOK = (int*)(H + (size_t)HCAP * HID);                    // [8][8192]
  float* BW  = (float*)(TOK + NE * T_TOKENS);                     // [8][8192]
  int*   CNT = (int*)(BW + NE * T_TOKENS);                        // [16]
  unsigned short* ZBUF = (unsigned short*)(CNT + 16);             // [1024] zeros
  int2*   SEL = (int2*)(ZBUF + 1024);                             // [8192]
  float2* WTS = (float2*)(SEL + T_TOKENS);                        // [8192]
  int2*   POS = (int2*)(WTS + T_TOKENS);                          // [8192]
  // Y (2 K-half partials, compact cn-prefix rows): 2 x YHALF bf16 = 67.1 MB
  // aliases W1T+W3T exactly (dead after gemm1)
  unsigned short* Y = W1T;

  prep_kernel<<<14336, 256, 0, stream>>>(x, gw, w1, w3, w2, W1T, W3T, W2T,
                                         SEL, WTS, XB, CNT, ZBUF);
  scatter_kernel<<<T_TOKENS / 256, 256, 0, stream>>>(SEL, WTS, CNT, TOK, BW, POS);
  gemm1_kernel<<<dim3(HID / 64, 64, NE), 256, 0, stream>>>(XB, W1T, W3T, CNT, TOK, ZBUF, H);
  gemm2_kernel<<<dim3((DIM / 128) * 2, 64, NE), 256, 0, stream>>>(H, W2T, CNT, BW, Y);
  combine_kernel<<<T_TOKENS / 2, 256, 0, stream>>>(Y, SEL, POS, CNT, out);
}